// Round 10
// baseline (473.310 us; speedup 1.0000x reference)
//
#include <hip/hip_runtime.h>
#include <hip/hip_fp16.h>

#define DIM 256
#define MAXMEM 16

typedef _Float16 f16x8 __attribute__((ext_vector_type(8)));
typedef float f32x4 __attribute__((ext_vector_type(4)));

__device__ inline unsigned short f2h(float f) {
  return __half_as_ushort(__float2half_rn(f));
}
__device__ inline float h2f(unsigned short u) {
  return __half2float(__ushort_as_half(u));
}

// ---------------------------------------------------------------------------
// Layer-0 fused: h[N x 256] = x[N x 3] @ W (fp16 out) + attention dots (f32).
__global__ __launch_bounds__(256) void l0_fused(
    const float* __restrict__ x, const float* __restrict__ W,
    const float* __restrict__ asv, const float* __restrict__ adv,
    unsigned short* __restrict__ h, float* __restrict__ ssrc,
    float* __restrict__ sdst, int N) {
  int wid = (blockIdx.x * 256 + threadIdx.x) >> 6;
  int lane = threadIdx.x & 63;
  if (wid >= N) return;
  float x0 = x[wid * 3 + 0], x1 = x[wid * 3 + 1], x2 = x[wid * 3 + 2];
  int c = lane * 4;
  float4 w0 = *(const float4*)(W + c);
  float4 w1 = *(const float4*)(W + 256 + c);
  float4 w2 = *(const float4*)(W + 512 + c);
  float4 hv;
  hv.x = fmaf(x0, w0.x, fmaf(x1, w1.x, x2 * w2.x));
  hv.y = fmaf(x0, w0.y, fmaf(x1, w1.y, x2 * w2.y));
  hv.z = fmaf(x0, w0.z, fmaf(x1, w1.z, x2 * w2.z));
  hv.w = fmaf(x0, w0.w, fmaf(x1, w1.w, x2 * w2.w));
  ((ushort4*)(h + (size_t)wid * DIM))[lane] =
      make_ushort4(f2h(hv.x), f2h(hv.y), f2h(hv.z), f2h(hv.w));
  float4 a1 = ((const float4*)asv)[lane];
  float4 a2 = ((const float4*)adv)[lane];
  float d1 = hv.x * a1.x + hv.y * a1.y + hv.z * a1.z + hv.w * a1.w;
  float d2 = hv.x * a2.x + hv.y * a2.y + hv.z * a2.z + hv.w * a2.w;
  for (int o = 32; o > 0; o >>= 1) {
    d1 += __shfl_down(d1, o);
    d2 += __shfl_down(d2, o);
  }
  if (lane == 0) { ssrc[wid] = d1; sdst[wid] = d2; }
}

// ---------------------------------------------------------------------------
// Weight prep: fold normalization into W (fp16 Wt transposed + cvec).
__global__ __launch_bounds__(256) void prep_k(
    const float* __restrict__ W, const float* __restrict__ sums,
    const float* __restrict__ sqs, float invN,
    unsigned short* __restrict__ Wt, float* __restrict__ cvec) {
  int n = blockIdx.x;   // output column
  int k = threadIdx.x;  // input channel
  float mu = sums[k] * invN;
  float var = sqs[k] * invN - mu * mu;
  float istd = rsqrtf(var + 1e-5f);
  float w = W[(size_t)k * 256 + n] * istd;
  Wt[(size_t)n * 256 + k] = f2h(w);
  __shared__ float red[256];
  red[k] = mu * w;
  __syncthreads();
  for (int s = 128; s > 0; s >>= 1) {
    if (k < s) red[k] += red[k + s];
    __syncthreads();
  }
  if (k == 0) cvec[n] = -red[0];
}

// ---------------------------------------------------------------------------
// MFMA fp16 GEMM + fused attention dots (dots from fp32 accumulators).
__global__ __launch_bounds__(256) void gemm_mfma(
    const unsigned short* __restrict__ A, const unsigned short* __restrict__ Wt,
    const float* __restrict__ cvec, const float* __restrict__ asv,
    const float* __restrict__ adv, unsigned short* __restrict__ H,
    float* __restrict__ ssrc, float* __restrict__ sdst, int M) {
  __shared__ unsigned short Bs[2][256 * 32];  // 16 KB per buffer
  int tid = threadIdx.x;
  int wave = tid >> 6, lane = tid & 63;
  int m0 = blockIdx.x * 64 + wave * 16;
  int row = lane & 15, quad = lane >> 4;

#pragma unroll
  for (int i = 0; i < 4; i++) {
    int c = i * 256 + tid;
    f16x8 v = *(const f16x8*)(const void*)(Wt + (size_t)(c >> 2) * 256 + (c & 3) * 8);
    *(f16x8*)(void*)(&Bs[0][c * 8]) = v;
  }
  __syncthreads();

  const unsigned short* Ap = A + (size_t)(m0 + row) * 256 + quad * 8;
  f32x4 acc[16] = {};
  for (int j = 0; j < 8; j++) {
    f16x8 pf[4];
    if (j < 7) {
#pragma unroll
      for (int i = 0; i < 4; i++) {
        int c = i * 256 + tid;
        pf[i] = *(const f16x8*)(const void*)(Wt + (size_t)(c >> 2) * 256 +
                                             (j + 1) * 32 + (c & 3) * 8);
      }
    }
    f16x8 a = *(const f16x8*)(const void*)(Ap + j * 32);
    const unsigned short* bs = Bs[j & 1];
#pragma unroll
    for (int nt = 0; nt < 16; nt++) {
      f16x8 b = *(const f16x8*)(const void*)(bs + (nt * 16 + row) * 32 + quad * 8);
      acc[nt] = __builtin_amdgcn_mfma_f32_16x16x32_f16(a, b, acc[nt], 0, 0, 0);
    }
    if (j < 7) {
#pragma unroll
      for (int i = 0; i < 4; i++) {
        int c = i * 256 + tid;
        *(f16x8*)(void*)(&Bs[(j + 1) & 1][c * 8]) = pf[i];
      }
    }
    __syncthreads();
  }

  float sav[16], sdv[16], cv[16];
#pragma unroll
  for (int nt = 0; nt < 16; nt++) {
    sav[nt] = asv[nt * 16 + row];
    sdv[nt] = adv[nt * 16 + row];
    cv[nt] = cvec[nt * 16 + row];
  }
#pragma unroll
  for (int r = 0; r < 4; r++) {
    int mm = m0 + quad * 4 + r;
    unsigned short* out = H + (size_t)mm * 256 + row;
    float d1 = 0.f, d2 = 0.f;
#pragma unroll
    for (int nt = 0; nt < 16; nt++) {
      float hv = acc[nt][r] + cv[nt];
      out[nt * 16] = f2h(hv);
      d1 = fmaf(hv, sav[nt], d1);
      d2 = fmaf(hv, sdv[nt], d2);
    }
    for (int o = 1; o < 16; o <<= 1) {
      d1 += __shfl_xor(d1, o);
      d2 += __shfl_xor(d2, o);
    }
    if (row == 0) { ssrc[mm] = d1; sdst[mm] = d2; }
  }
}

// ---------------------------------------------------------------------------
// BASE-graph bucketing (topology replicated across B graphs).
__global__ void base_bucket_k(
    const int* __restrict__ esrc, const int* __restrict__ edst, int Eb,
    int* __restrict__ bdeg, int* __restrict__ bebkt, int estride,
    const int* __restrict__ cluster, int Nb,
    int* __restrict__ bccnt, int* __restrict__ bcbkt) {
  int i = blockIdx.x * 256 + threadIdx.x;
  if (i < Eb) {
    int d = edst[i];
    int slot = atomicAdd(&bdeg[d], 1);
    if (slot < estride) bebkt[d * estride + slot] = esrc[i];
  }
  if (i < Nb) {
    int c = cluster[i];
    int slot = atomicAdd(&bccnt[c], 1);
    if (slot < MAXMEM) bcbkt[c * MAXMEM + slot] = i;
  }
}

// ---------------------------------------------------------------------------
// Edge scores per (graph, base-dst): NORMALIZED alpha = p / sum(p) stored.
__global__ __launch_bounds__(256) void score_k(
    const int* __restrict__ bdeg, const int* __restrict__ bebkt, int estride,
    const float* __restrict__ ssrc, const float* __restrict__ sdst,
    float* __restrict__ pw, int Nb) {
  int d = blockIdx.x * 256 + threadIdx.x;
  int g = blockIdx.y;
  if (d >= Nb) return;
  int gOff = g * Nb;
  int deg = bdeg[d]; if (deg > estride) deg = estride;
  float sd = sdst[gOff + d];
  const int* bk = bebkt + d * estride;
  float* pwr = pw + (size_t)(gOff + d) * estride;
  float sum = 0.f;
  for (int j = 0; j < deg; j++) {
    int s = bk[j];
    float t = ssrc[gOff + s] + sd;
    t = t > 0.f ? t : 0.2f * t;  // leaky_relu 0.2
    float p = __expf(t);
    pwr[j] = p;
    sum += p;
  }
  float inv = 1.f / sum;  // deg >= 1 (self-loop)
  for (int j = 0; j < deg; j++) pwr[j] *= inv;
}

// ---------------------------------------------------------------------------
// Fused GAT aggregation + bias + relu + cluster max-pool (fp16 h, fp16 out).
// Wave per output row (g, c). Lane = 32*e + ch: half-waves process 2 edges
// per round, each lane loads 16 B (8 fp16 channels) and accumulates with
// v_pk_fma_f16 (alpha pre-normalized -> no overflow, no division here).
// One cross-half reduce per MEMBER recombines the two halves.
__global__ __launch_bounds__(256) void gat_pool(
    const unsigned short* __restrict__ h, const int* __restrict__ bdeg,
    const int* __restrict__ bebkt, const float* __restrict__ pw, int estride,
    const int* __restrict__ bccnt, const int* __restrict__ bcbkt,
    const float* __restrict__ bias, unsigned short* __restrict__ pooled,
    int M, int gb, int Nb, int lgMb) {
  int b = blockIdx.x;
  int x = b & 7, t = b >> 3;
  int l = (x + 8 * (t / gb)) * gb + (t % gb);  // XCD-local logical block
  int wid = l * 4 + (threadIdx.x >> 6);
  int lane = threadIdx.x & 63;
  if (wid >= M) return;
  int e = lane >> 5;        // edge half
  int ch = lane & 31;       // channel group (8 fp16 each)
  int g = wid >> lgMb;
  int c = wid & ((1 << lgMb) - 1);
  int gOff = g * Nb;
  const unsigned short* hg = h + (size_t)gOff * DIM;
  int nm = __builtin_amdgcn_readfirstlane(bccnt[c]);
  if (nm > MAXMEM) nm = MAXMEM;
  float4 bv0 = *(const float4*)(bias + ch * 8);
  float4 bv1 = *(const float4*)(bias + ch * 8 + 4);
  float best[8] = {0.f, 0.f, 0.f, 0.f, 0.f, 0.f, 0.f, 0.f};  // relu fold
  for (int mi = 0; mi < nm; mi++) {
    int nb = __builtin_amdgcn_readfirstlane(bcbkt[c * MAXMEM + mi]);
    int deg = __builtin_amdgcn_readfirstlane(bdeg[nb]);
    if (deg > estride) deg = estride;
    const int* bk = bebkt + nb * estride;              // uniform, L1-hot
    const float* pwn = pw + (size_t)(gOff + nb) * estride;
    __half2 acc[4];
#pragma unroll
    for (int i = 0; i < 4; i++) acc[i] = __float2half2_rn(0.f);
    int j = 0;
    for (; j + 8 <= deg; j += 8) {
#pragma unroll
      for (int r = 0; r < 4; r++) {
        int2 aa = *(const int2*)(bk + j + 2 * r);       // broadcast 8B
        float2 qq = *(const float2*)(pwn + j + 2 * r);  // broadcast 8B
        int a = e ? aa.y : aa.x;
        float q = e ? qq.y : qq.x;
        uint4 hv = ((const uint4*)(hg + (size_t)a * DIM))[ch];
        __half2 hq = __float2half2_rn(q);
        union { uint4 u; __half2 p[4]; } uu; uu.u = hv;
#pragma unroll
        for (int i = 0; i < 4; i++) acc[i] = __hfma2(uu.p[i], hq, acc[i]);
      }
    }
    for (; j < deg; j += 2) {
      int idx = j + e;
      bool v = idx < deg;
      int a = bk[v ? idx : j];
      float q = v ? pwn[idx] : 0.f;
      uint4 hv = ((const uint4*)(hg + (size_t)a * DIM))[ch];
      __half2 hq = __float2half2_rn(q);
      union { uint4 u; __half2 p[4]; } uu; uu.u = hv;
#pragma unroll
      for (int i = 0; i < 4; i++) acc[i] = __hfma2(uu.p[i], hq, acc[i]);
    }
    // cross-half reduce (edge halves sum) + fold into f32 best with bias.
    float bb[8] = {bv0.x, bv0.y, bv0.z, bv0.w, bv1.x, bv1.y, bv1.z, bv1.w};
#pragma unroll
    for (int i = 0; i < 4; i++) {
      int ai = *(int*)&acc[i];
      int bi = __shfl_xor(ai, 32);
      __half2 s = __hadd2(acc[i], *(__half2*)&bi);
      float2 f = __half22float2(s);
      best[2 * i]     = fmaxf(best[2 * i],     f.x + bb[2 * i]);
      best[2 * i + 1] = fmaxf(best[2 * i + 1], f.y + bb[2 * i + 1]);
    }
  }
  if (e == 0) {
    union { uint4 u; __half2 p[4]; } out;
#pragma unroll
    for (int i = 0; i < 4; i++)
      out.p[i] = __floats2half2_rn(best[2 * i], best[2 * i + 1]);
    ((uint4*)(pooled + (size_t)wid * DIM))[ch] = out.u;
  }
}

// ---------------------------------------------------------------------------
// Channel sums over M rows (axis 0), fp16 input.
__global__ void stats_k(const unsigned short* __restrict__ x,
                        float* __restrict__ sums, float* __restrict__ sqs, int M) {
  int c = threadIdx.x;
  float s = 0.f, q = 0.f;
  for (int r = blockIdx.x; r < M; r += gridDim.x) {
    float v = h2f(x[(size_t)r * DIM + c]);
    s += v; q = fmaf(v, v, q);
  }
  atomicAdd(&sums[c], s);
  atomicAdd(&sqs[c], q);
}

// Final normalize: fp16 pooled -> fp32 d_out.
__global__ void norm_out(const unsigned short* __restrict__ xin,
                         float* __restrict__ xout,
                         const float* __restrict__ sums, const float* __restrict__ sqs,
                         float invN, int total) {
  int idx = blockIdx.x * 256 + threadIdx.x;
  if (idx >= total) return;
  int c = idx & 255;
  float mu = sums[c] * invN;
  float var = sqs[c] * invN - mu * mu;
  xout[idx] = (h2f(xin[idx]) - mu) * rsqrtf(var + 1e-5f);
}

// ---------------------------------------------------------------------------
extern "C" void kernel_launch(void* const* d_in, const int* in_sizes, int n_in,
                              void* d_out, int out_size, void* d_ws, size_t ws_size,
                              hipStream_t stream) {
  const int B = 128;
  const int Nb[4] = {706, 512, 256, 128};          // base-graph sizes
  const int Ns[4] = {128 * 706, 128 * 512, 128 * 256, 128 * 128};
  const int lgMb[3] = {9, 8, 7};                   // log2(Nb[L+1])
  const int EST[3] = {64, 160, 288};               // base in-degree strides

  int iW[3], iA[3], iD[3], iB_[3], iE[3], iC[3];
  if (in_sizes[2] == 256) {  // dict order
    for (int i = 0; i < 3; i++) {
      iW[i] = 1 + 6 * i; iA[i] = 2 + 6 * i; iD[i] = 3 + 6 * i;
      iB_[i] = 4 + 6 * i; iE[i] = 5 + 6 * i; iC[i] = 6 + 6 * i;
    }
  } else {
    for (int i = 0; i < 3; i++) {
      iW[i] = 1 + i; iA[i] = 4 + i; iD[i] = 7 + i;
      iB_[i] = 10 + i; iE[i] = 13 + i; iC[i] = 16 + i;
    }
  }
  int E[3];
  for (int i = 0; i < 3; i++) E[i] = in_sizes[iE[i]] / 2;

  size_t pwWords = 0;
  for (int i = 0; i < 3; i++) {
    size_t w = (size_t)Ns[i] * EST[i];
    if (w > pwWords) pwWords = w;
  }
  size_t bebktWords = 0;
  for (int i = 0; i < 3; i++) {
    size_t w = (size_t)Nb[i] * EST[i];
    if (w > bebktWords) bebktWords = w;
  }

  char* wsp = (char*)d_ws;
  size_t o = 0;
  auto alloc = [&](size_t bytes) -> void* {
    void* p = wsp + o;
    o = (o + bytes + 255) & ~(size_t)255;
    return p;
  };
  unsigned short* h      = (unsigned short*)alloc((size_t)Ns[0] * DIM * 2);  // 46 MB
  unsigned short* pooled = (unsigned short*)alloc((size_t)Ns[1] * DIM * 2);  // 33.5 MB
  float* ssrc   = (float*)alloc((size_t)Ns[0] * 4);
  float* sdst   = (float*)alloc((size_t)Ns[0] * 4);
  float* pw     = (float*)alloc(pwWords * 4);                    // 42 MB
  int*   bmeta  = (int*)alloc((size_t)(Nb[0] + Nb[1]) * 4);      // bdeg|bccnt
  int*   bebkt  = (int*)alloc(bebktWords * 4);                   // ~300 KB
  int*   bcbkt  = (int*)alloc((size_t)Nb[1] * MAXMEM * 4);       // 32 KB
  float* statbuf= (float*)alloc(3 * 512 * 4);
  unsigned short* Wt = (unsigned short*)alloc(256 * 256 * 2);
  float* cvec   = (float*)alloc(256 * 4);
  (void)ws_size; (void)n_in; (void)out_size;

  int* bdeg = bmeta;
  int* bccnt = bmeta + Nb[0];
  const float* xin = (const float*)d_in[0];

  hipMemsetAsync(statbuf, 0, 3 * 512 * 4, stream);

  for (int L = 0; L < 3; L++) {
    int N = Ns[L], M = Ns[L + 1];
    int NbL = Nb[L], Eb = E[L] / B;
    const float* W  = (const float*)d_in[iW[L]];
    const float* av = (const float*)d_in[iA[L]];
    const float* dv = (const float*)d_in[iD[L]];
    const float* bv = (const float*)d_in[iB_[L]];
    const int* esrc = (const int*)d_in[iE[L]];
    const int* edst = esrc + E[L];
    const int* cl   = (const int*)d_in[iC[L]];
    float* sums = statbuf + L * 512;
    float* sqs  = sums + 256;

    hipMemsetAsync(bmeta, 0, (size_t)(Nb[0] + Nb[1]) * 4, stream);
    int gmax = Eb > NbL ? Eb : NbL;
    base_bucket_k<<<(gmax + 255) / 256, 256, 0, stream>>>(
        esrc, edst, Eb, bdeg, bebkt, EST[L], cl, NbL, bccnt, bcbkt);

    if (L == 0) {
      l0_fused<<<(N + 3) / 4, 256, 0, stream>>>(xin, W, av, dv, h, ssrc, sdst, N);
    } else {
      float* psums = statbuf + (L - 1) * 512;
      prep_k<<<256, 256, 0, stream>>>(W, psums, psums + 256, 1.0f / (float)N,
                                      Wt, cvec);
      gemm_mfma<<<N / 64, 256, 0, stream>>>(pooled, Wt, cvec, av, dv,
                                            h, ssrc, sdst, N);
    }

    dim3 sg((NbL + 255) / 256, B);
    score_k<<<sg, 256, 0, stream>>>(bdeg, bebkt, EST[L], ssrc, sdst, pw, NbL);

    gat_pool<<<M / 4, 256, 0, stream>>>(h, bdeg, bebkt, pw, EST[L],
                                        bccnt, bcbkt, bv, pooled, M, M / 512,
                                        NbL, lgMb[L]);

    stats_k<<<512, 256, 0, stream>>>(pooled, sums, sqs, M);
  }

  norm_out<<<((size_t)Ns[3] * DIM + 255) / 256, 256, 0, stream>>>(
      pooled, (float*)d_out, statbuf + 2 * 512, statbuf + 2 * 512 + 256,
      1.0f / (float)Ns[3], Ns[3] * DIM);
}

// Round 11
// 436.331 us; speedup vs baseline: 1.0847x; 1.0847x over previous
//
#include <hip/hip_runtime.h>
#include <hip/hip_fp16.h>

#define DIM 256
#define MAXMEM 16

typedef _Float16 f16x8 __attribute__((ext_vector_type(8)));
typedef float f32x4 __attribute__((ext_vector_type(4)));

__device__ inline unsigned short f2h(float f) {
  return __half_as_ushort(__float2half_rn(f));
}
__device__ inline float h2f(unsigned short u) {
  return __half2float(__ushort_as_half(u));
}
__device__ inline __half2 hmax2_(__half2 a, __half2 b) {
  __half2 c;
  c.x = __hgt(a.x, b.x) ? a.x : b.x;
  c.y = __hgt(a.y, b.y) ? a.y : b.y;
  return c;
}

// ---------------------------------------------------------------------------
// NODE ORDERING: base-major. Global row index of (base node nb, graph g) is
// nb*128 + g.  (Reference order is g*Nb + nb; only x-read and final output
// permute.)  h/pooled rows, ssrc/sdst all use base-major indices.
// ---------------------------------------------------------------------------

// Layer-0 fused: h = x @ W (fp16 out, base-major rows) + attention dots.
__global__ __launch_bounds__(256) void l0_fused(
    const float* __restrict__ x, const float* __restrict__ W,
    const float* __restrict__ asv, const float* __restrict__ adv,
    unsigned short* __restrict__ h, float* __restrict__ ssrc,
    float* __restrict__ sdst, int N, int Nb0) {
  int wid = (blockIdx.x * 256 + threadIdx.x) >> 6;  // nb*128+g
  int lane = threadIdx.x & 63;
  if (wid >= N) return;
  int nb = wid >> 7, g = wid & 127;
  const float* xr = x + ((size_t)g * Nb0 + nb) * 3;  // reference is graph-major
  float x0 = xr[0], x1 = xr[1], x2 = xr[2];
  int c = lane * 4;
  float4 w0 = *(const float4*)(W + c);
  float4 w1 = *(const float4*)(W + 256 + c);
  float4 w2 = *(const float4*)(W + 512 + c);
  float4 hv;
  hv.x = fmaf(x0, w0.x, fmaf(x1, w1.x, x2 * w2.x));
  hv.y = fmaf(x0, w0.y, fmaf(x1, w1.y, x2 * w2.y));
  hv.z = fmaf(x0, w0.z, fmaf(x1, w1.z, x2 * w2.z));
  hv.w = fmaf(x0, w0.w, fmaf(x1, w1.w, x2 * w2.w));
  ((ushort4*)(h + (size_t)wid * DIM))[lane] =
      make_ushort4(f2h(hv.x), f2h(hv.y), f2h(hv.z), f2h(hv.w));
  float4 a1 = ((const float4*)asv)[lane];
  float4 a2 = ((const float4*)adv)[lane];
  float d1 = hv.x * a1.x + hv.y * a1.y + hv.z * a1.z + hv.w * a1.w;
  float d2 = hv.x * a2.x + hv.y * a2.y + hv.z * a2.z + hv.w * a2.w;
  for (int o = 32; o > 0; o >>= 1) {
    d1 += __shfl_down(d1, o);
    d2 += __shfl_down(d2, o);
  }
  if (lane == 0) { ssrc[wid] = d1; sdst[wid] = d2; }
}

// ---------------------------------------------------------------------------
// Weight prep: fold normalization into W (fp16 Wt transposed + cvec).
__global__ __launch_bounds__(256) void prep_k(
    const float* __restrict__ W, const float* __restrict__ sums,
    const float* __restrict__ sqs, float invN,
    unsigned short* __restrict__ Wt, float* __restrict__ cvec) {
  int n = blockIdx.x;
  int k = threadIdx.x;
  float mu = sums[k] * invN;
  float var = sqs[k] * invN - mu * mu;
  float istd = rsqrtf(var + 1e-5f);
  float w = W[(size_t)k * 256 + n] * istd;
  Wt[(size_t)n * 256 + k] = f2h(w);
  __shared__ float red[256];
  red[k] = mu * w;
  __syncthreads();
  for (int s = 128; s > 0; s >>= 1) {
    if (k < s) red[k] += red[k + s];
    __syncthreads();
  }
  if (k == 0) cvec[n] = -red[0];
}

// ---------------------------------------------------------------------------
// MFMA fp16 GEMM + fused attention dots (row-order agnostic).
__global__ __launch_bounds__(256) void gemm_mfma(
    const unsigned short* __restrict__ A, const unsigned short* __restrict__ Wt,
    const float* __restrict__ cvec, const float* __restrict__ asv,
    const float* __restrict__ adv, unsigned short* __restrict__ H,
    float* __restrict__ ssrc, float* __restrict__ sdst, int M) {
  __shared__ unsigned short Bs[2][256 * 32];  // 16 KB per buffer
  int tid = threadIdx.x;
  int wave = tid >> 6, lane = tid & 63;
  int m0 = blockIdx.x * 64 + wave * 16;
  int row = lane & 15, quad = lane >> 4;

#pragma unroll
  for (int i = 0; i < 4; i++) {
    int c = i * 256 + tid;
    f16x8 v = *(const f16x8*)(const void*)(Wt + (size_t)(c >> 2) * 256 + (c & 3) * 8);
    *(f16x8*)(void*)(&Bs[0][c * 8]) = v;
  }
  __syncthreads();

  const unsigned short* Ap = A + (size_t)(m0 + row) * 256 + quad * 8;
  f32x4 acc[16] = {};
  for (int j = 0; j < 8; j++) {
    f16x8 pf[4];
    if (j < 7) {
#pragma unroll
      for (int i = 0; i < 4; i++) {
        int c = i * 256 + tid;
        pf[i] = *(const f16x8*)(const void*)(Wt + (size_t)(c >> 2) * 256 +
                                             (j + 1) * 32 + (c & 3) * 8);
      }
    }
    f16x8 a = *(const f16x8*)(const void*)(Ap + j * 32);
    const unsigned short* bs = Bs[j & 1];
#pragma unroll
    for (int nt = 0; nt < 16; nt++) {
      f16x8 b = *(const f16x8*)(const void*)(bs + (nt * 16 + row) * 32 + quad * 8);
      acc[nt] = __builtin_amdgcn_mfma_f32_16x16x32_f16(a, b, acc[nt], 0, 0, 0);
    }
    if (j < 7) {
#pragma unroll
      for (int i = 0; i < 4; i++) {
        int c = i * 256 + tid;
        *(f16x8*)(void*)(&Bs[(j + 1) & 1][c * 8]) = pf[i];
      }
    }
    __syncthreads();
  }

  float sav[16], sdv[16], cv[16];
#pragma unroll
  for (int nt = 0; nt < 16; nt++) {
    sav[nt] = asv[nt * 16 + row];
    sdv[nt] = adv[nt * 16 + row];
    cv[nt] = cvec[nt * 16 + row];
  }
#pragma unroll
  for (int r = 0; r < 4; r++) {
    int mm = m0 + quad * 4 + r;
    unsigned short* out = H + (size_t)mm * 256 + row;
    float d1 = 0.f, d2 = 0.f;
#pragma unroll
    for (int nt = 0; nt < 16; nt++) {
      float hv = acc[nt][r] + cv[nt];
      out[nt * 16] = f2h(hv);
      d1 = fmaf(hv, sav[nt], d1);
      d2 = fmaf(hv, sdv[nt], d2);
    }
    for (int o = 1; o < 16; o <<= 1) {
      d1 += __shfl_xor(d1, o);
      d2 += __shfl_xor(d2, o);
    }
    if (row == 0) { ssrc[mm] = d1; sdst[mm] = d2; }
  }
}

// ---------------------------------------------------------------------------
// BASE-graph bucketing (topology replicated across the 128 graphs).
__global__ void base_bucket_k(
    const int* __restrict__ esrc, const int* __restrict__ edst, int Eb,
    int* __restrict__ bdeg, int* __restrict__ bebkt, int estride,
    const int* __restrict__ cluster, int Nb,
    int* __restrict__ bccnt, int* __restrict__ bcbkt) {
  int i = blockIdx.x * 256 + threadIdx.x;
  if (i < Eb) {
    int d = edst[i];
    int slot = atomicAdd(&bdeg[d], 1);
    if (slot < estride) bebkt[d * estride + slot] = esrc[i];
  }
  if (i < Nb) {
    int c = cluster[i];
    int slot = atomicAdd(&bccnt[c], 1);
    if (slot < MAXMEM) bcbkt[c * MAXMEM + slot] = i;
  }
}

// ---------------------------------------------------------------------------
// Edge scores, thread = (base dst d, graph g): normalized alpha stored at
// pw[(d*stride + j)*128 + g] (graph-contiguous -> coalesced both ways).
__global__ __launch_bounds__(256) void score_k(
    const int* __restrict__ bdeg, const int* __restrict__ bebkt, int estride,
    const float* __restrict__ ssrc, const float* __restrict__ sdst,
    float* __restrict__ pw, int Nb) {
  int id = blockIdx.x * 256 + threadIdx.x;
  if (id >= Nb * 128) return;
  int d = id >> 7, g = id & 127;
  int deg = bdeg[d]; if (deg > estride) deg = estride;
  float sd = sdst[d * 128 + g];
  const int* bk = bebkt + d * estride;
  float* pwr = pw + (size_t)d * estride * 128 + g;
  float sum = 0.f;
  for (int j = 0; j < deg; j++) {
    int s = bk[j];                      // uniform per d (L1 broadcast)
    float t = ssrc[s * 128 + g] + sd;   // coalesced across g
    t = t > 0.f ? t : 0.2f * t;         // leaky_relu 0.2
    float p = __expf(t);
    pwr[j * 128] = p;
    sum += p;
  }
  float inv = 1.f / sum;                // deg >= 1 (self-loop)
  for (int j = 0; j < deg; j++) pwr[j * 128] *= inv;
}

// ---------------------------------------------------------------------------
// Fused GAT aggregation + bias + relu + cluster max-pool, graph-batched.
// Block = (base output cluster c, set of 8 graphs); thread = (graph g_local,
// 8-channel chunk). Every h load is part of one coalesced 4 KB block read;
// meta amortized over 256 threads; zero cross-lane ops. Set pinned to an XCD
// via b%8 swizzle so the 8-graph h slice stays L2-resident.
__global__ __launch_bounds__(256) void gat_pool(
    const unsigned short* __restrict__ h, const int* __restrict__ bdeg,
    const int* __restrict__ bebkt, const float* __restrict__ pw, int estride,
    const int* __restrict__ bccnt, const int* __restrict__ bcbkt,
    const float* __restrict__ bias, unsigned short* __restrict__ pooled,
    int Mb, int lgMb) {
  int b = blockIdx.x;                 // grid = Mb * 16
  int x = b & 7, t = b >> 3;
  int c = t & (Mb - 1);
  int set = x + 8 * (t >> lgMb);      // 0..15, pinned: b%8 == set%8
  int tid = threadIdx.x;
  int gl = tid >> 5;                  // graph within set (0..7)
  int ch = tid & 31;                  // channel chunk (8 fp16 = 16 B)
  int g = set * 8 + gl;
  int nm = bccnt[c]; if (nm > MAXMEM) nm = MAXMEM;
  float4 bf0 = *(const float4*)(bias + ch * 8);
  float4 bf1 = *(const float4*)(bias + ch * 8 + 4);
  __half2 hb[4] = {__floats2half2_rn(bf0.x, bf0.y), __floats2half2_rn(bf0.z, bf0.w),
                   __floats2half2_rn(bf1.x, bf1.y), __floats2half2_rn(bf1.z, bf1.w)};
  __half2 z = __float2half2_rn(0.f);
  __half2 best[4] = {z, z, z, z};     // relu folded via 0-init
  for (int mi = 0; mi < nm; mi++) {
    int nb = __builtin_amdgcn_readfirstlane(bcbkt[c * MAXMEM + mi]);
    int deg = __builtin_amdgcn_readfirstlane(bdeg[nb]);
    if (deg > estride) deg = estride;
    const int* bk = bebkt + nb * estride;                  // uniform, L1-hot
    const float* pwn = pw + (size_t)nb * estride * 128 + g;
    __half2 acc[4] = {z, z, z, z};
    int j = 0;
    for (; j + 4 <= deg; j += 4) {
      int4 ss = *(const int4*)(bk + j);                    // broadcast 16B
      float q0 = pwn[(size_t)j * 128];
      float q1 = pwn[(size_t)(j + 1) * 128];
      float q2 = pwn[(size_t)(j + 2) * 128];
      float q3 = pwn[(size_t)(j + 3) * 128];
      uint4 v0 = *(const uint4*)(h + ((size_t)ss.x * 128 + g) * DIM + ch * 8);
      uint4 v1 = *(const uint4*)(h + ((size_t)ss.y * 128 + g) * DIM + ch * 8);
      uint4 v2 = *(const uint4*)(h + ((size_t)ss.z * 128 + g) * DIM + ch * 8);
      uint4 v3 = *(const uint4*)(h + ((size_t)ss.w * 128 + g) * DIM + ch * 8);
      __half2 hq0 = __float2half2_rn(q0), hq1 = __float2half2_rn(q1);
      __half2 hq2 = __float2half2_rn(q2), hq3 = __float2half2_rn(q3);
      union { uint4 u; __half2 p[4]; } u0, u1, u2, u3;
      u0.u = v0; u1.u = v1; u2.u = v2; u3.u = v3;
#pragma unroll
      for (int i = 0; i < 4; i++) {
        acc[i] = __hfma2(u0.p[i], hq0, acc[i]);
        acc[i] = __hfma2(u1.p[i], hq1, acc[i]);
        acc[i] = __hfma2(u2.p[i], hq2, acc[i]);
        acc[i] = __hfma2(u3.p[i], hq3, acc[i]);
      }
    }
    for (; j < deg; j++) {
      int s = bk[j];
      float q = pwn[(size_t)j * 128];
      uint4 v0 = *(const uint4*)(h + ((size_t)s * 128 + g) * DIM + ch * 8);
      __half2 hq = __float2half2_rn(q);
      union { uint4 u; __half2 p[4]; } u0; u0.u = v0;
#pragma unroll
      for (int i = 0; i < 4; i++) acc[i] = __hfma2(u0.p[i], hq, acc[i]);
    }
#pragma unroll
    for (int i = 0; i < 4; i++)
      best[i] = hmax2_(best[i], __hadd2(acc[i], hb[i]));
  }
  union { uint4 u; __half2 p[4]; } o;
#pragma unroll
  for (int i = 0; i < 4; i++) o.p[i] = best[i];
  *(uint4*)(pooled + ((size_t)c * 128 + g) * DIM + ch * 8) = o.u;
}

// ---------------------------------------------------------------------------
// Channel sums over M rows (axis 0), fp16 input (row order irrelevant).
__global__ void stats_k(const unsigned short* __restrict__ x,
                        float* __restrict__ sums, float* __restrict__ sqs, int M) {
  int c = threadIdx.x;
  float s = 0.f, q = 0.f;
  for (int r = blockIdx.x; r < M; r += gridDim.x) {
    float v = h2f(x[(size_t)r * DIM + c]);
    s += v; q = fmaf(v, v, q);
  }
  atomicAdd(&sums[c], s);
  atomicAdd(&sqs[c], q);
}

// Final normalize: fp16 pooled (base-major) -> fp32 d_out (graph-major).
__global__ void norm_out(const unsigned short* __restrict__ xin,
                         float* __restrict__ xout,
                         const float* __restrict__ sums, const float* __restrict__ sqs,
                         float invN, int Mb, int total) {
  int idx = blockIdx.x * 256 + threadIdx.x;
  if (idx >= total) return;
  int ch = idx & 255;
  int r = idx >> 8;            // r = c*128 + g
  int g = r & 127, c = r >> 7;
  float mu = sums[ch] * invN;
  float var = sqs[ch] * invN - mu * mu;
  float v = (h2f(xin[idx]) - mu) * rsqrtf(var + 1e-5f);
  xout[((size_t)g * Mb + c) * 256 + ch] = v;
}

// ---------------------------------------------------------------------------
extern "C" void kernel_launch(void* const* d_in, const int* in_sizes, int n_in,
                              void* d_out, int out_size, void* d_ws, size_t ws_size,
                              hipStream_t stream) {
  const int B = 128;
  const int Nb[4] = {706, 512, 256, 128};          // base-graph sizes
  const int Ns[4] = {128 * 706, 128 * 512, 128 * 256, 128 * 128};
  const int lgMb[3] = {9, 8, 7};                   // log2(Nb[L+1])
  const int EST[3] = {64, 160, 288};               // base in-degree strides

  int iW[3], iA[3], iD[3], iB_[3], iE[3], iC[3];
  if (in_sizes[2] == 256) {  // dict order
    for (int i = 0; i < 3; i++) {
      iW[i] = 1 + 6 * i; iA[i] = 2 + 6 * i; iD[i] = 3 + 6 * i;
      iB_[i] = 4 + 6 * i; iE[i] = 5 + 6 * i; iC[i] = 6 + 6 * i;
    }
  } else {
    for (int i = 0; i < 3; i++) {
      iW[i] = 1 + i; iA[i] = 4 + i; iD[i] = 7 + i;
      iB_[i] = 10 + i; iE[i] = 13 + i; iC[i] = 16 + i;
    }
  }
  int E[3];
  for (int i = 0; i < 3; i++) E[i] = in_sizes[iE[i]] / 2;

  size_t pwWords = 0;
  for (int i = 0; i < 3; i++) {
    size_t w = (size_t)Ns[i] * EST[i];
    if (w > pwWords) pwWords = w;
  }
  size_t bebktWords = 0;
  for (int i = 0; i < 3; i++) {
    size_t w = (size_t)Nb[i] * EST[i];
    if (w > bebktWords) bebktWords = w;
  }

  char* wsp = (char*)d_ws;
  size_t o = 0;
  auto alloc = [&](size_t bytes) -> void* {
    void* p = wsp + o;
    o = (o + bytes + 255) & ~(size_t)255;
    return p;
  };
  unsigned short* h      = (unsigned short*)alloc((size_t)Ns[0] * DIM * 2);  // 46 MB
  unsigned short* pooled = (unsigned short*)alloc((size_t)Ns[1] * DIM * 2);  // 33.5 MB
  float* ssrc   = (float*)alloc((size_t)Ns[0] * 4);
  float* sdst   = (float*)alloc((size_t)Ns[0] * 4);
  float* pw     = (float*)alloc(pwWords * 4);                    // 42 MB
  int*   bmeta  = (int*)alloc((size_t)(Nb[0] + Nb[1]) * 4);      // bdeg|bccnt
  int*   bebkt  = (int*)alloc(bebktWords * 4);                   // ~300 KB
  int*   bcbkt  = (int*)alloc((size_t)Nb[1] * MAXMEM * 4);       // 32 KB
  float* statbuf= (float*)alloc(3 * 512 * 4);
  unsigned short* Wt = (unsigned short*)alloc(256 * 256 * 2);
  float* cvec   = (float*)alloc(256 * 4);
  (void)ws_size; (void)n_in; (void)out_size;

  int* bdeg = bmeta;
  int* bccnt = bmeta + Nb[0];
  const float* xin = (const float*)d_in[0];

  hipMemsetAsync(statbuf, 0, 3 * 512 * 4, stream);

  for (int L = 0; L < 3; L++) {
    int N = Ns[L], M = Ns[L + 1];
    int NbL = Nb[L], Eb = E[L] / B;
    const float* W  = (const float*)d_in[iW[L]];
    const float* av = (const float*)d_in[iA[L]];
    const float* dv = (const float*)d_in[iD[L]];
    const float* bv = (const float*)d_in[iB_[L]];
    const int* esrc = (const int*)d_in[iE[L]];
    const int* edst = esrc + E[L];
    const int* cl   = (const int*)d_in[iC[L]];
    float* sums = statbuf + L * 512;
    float* sqs  = sums + 256;

    hipMemsetAsync(bmeta, 0, (size_t)(Nb[0] + Nb[1]) * 4, stream);
    int gmax = Eb > NbL ? Eb : NbL;
    base_bucket_k<<<(gmax + 255) / 256, 256, 0, stream>>>(
        esrc, edst, Eb, bdeg, bebkt, EST[L], cl, NbL, bccnt, bcbkt);

    if (L == 0) {
      l0_fused<<<(N + 3) / 4, 256, 0, stream>>>(xin, W, av, dv, h, ssrc, sdst,
                                                N, NbL);
    } else {
      float* psums = statbuf + (L - 1) * 512;
      prep_k<<<256, 256, 0, stream>>>(W, psums, psums + 256, 1.0f / (float)N,
                                      Wt, cvec);
      gemm_mfma<<<N / 64, 256, 0, stream>>>(pooled, Wt, cvec, av, dv,
                                            h, ssrc, sdst, N);
    }

    score_k<<<(NbL * 128 + 255) / 256, 256, 0, stream>>>(
        bdeg, bebkt, EST[L], ssrc, sdst, pw, NbL);

    int MbL = Nb[L + 1];
    gat_pool<<<MbL * 16, 256, 0, stream>>>(h, bdeg, bebkt, pw, EST[L],
                                           bccnt, bcbkt, bv, pooled,
                                           MbL, lgMb[L]);

    stats_k<<<512, 256, 0, stream>>>(pooled, sums, sqs, M);
  }

  norm_out<<<((size_t)Ns[3] * DIM + 255) / 256, 256, 0, stream>>>(
      pooled, (float*)d_out, statbuf + 2 * 512, statbuf + 2 * 512 + 256,
      1.0f / (float)Ns[3], Nb[3], Ns[3] * DIM);
}

// Round 12
// 416.279 us; speedup vs baseline: 1.1370x; 1.0482x over previous
//
#include <hip/hip_runtime.h>
#include <hip/hip_fp16.h>

#define DIM 256
#define MAXMEM 16

typedef _Float16 f16x8 __attribute__((ext_vector_type(8)));
typedef float f32x4 __attribute__((ext_vector_type(4)));

__device__ inline unsigned short f2h(float f) {
  return __half_as_ushort(__float2half_rn(f));
}
__device__ inline float h2f(unsigned short u) {
  return __half2float(__ushort_as_half(u));
}
__device__ inline __half2 hmax2_(__half2 a, __half2 b) {
  __half2 c;
  c.x = __hgt(a.x, b.x) ? a.x : b.x;
  c.y = __hgt(a.y, b.y) ? a.y : b.y;
  return c;
}

// ---------------------------------------------------------------------------
// NODE ORDERING: base-major. Global row of (base node nb, graph g) = nb*128+g.
// ---------------------------------------------------------------------------

// Layer-0 fused: h = x @ W (fp16 out, base-major rows) + attention dots.
__global__ __launch_bounds__(256) void l0_fused(
    const float* __restrict__ x, const float* __restrict__ W,
    const float* __restrict__ asv, const float* __restrict__ adv,
    unsigned short* __restrict__ h, float* __restrict__ ssrc,
    float* __restrict__ sdst, int N, int Nb0) {
  int wid = (blockIdx.x * 256 + threadIdx.x) >> 6;  // nb*128+g
  int lane = threadIdx.x & 63;
  if (wid >= N) return;
  int nb = wid >> 7, g = wid & 127;
  const float* xr = x + ((size_t)g * Nb0 + nb) * 3;  // reference is graph-major
  float x0 = xr[0], x1 = xr[1], x2 = xr[2];
  int c = lane * 4;
  float4 w0 = *(const float4*)(W + c);
  float4 w1 = *(const float4*)(W + 256 + c);
  float4 w2 = *(const float4*)(W + 512 + c);
  float4 hv;
  hv.x = fmaf(x0, w0.x, fmaf(x1, w1.x, x2 * w2.x));
  hv.y = fmaf(x0, w0.y, fmaf(x1, w1.y, x2 * w2.y));
  hv.z = fmaf(x0, w0.z, fmaf(x1, w1.z, x2 * w2.z));
  hv.w = fmaf(x0, w0.w, fmaf(x1, w1.w, x2 * w2.w));
  ((ushort4*)(h + (size_t)wid * DIM))[lane] =
      make_ushort4(f2h(hv.x), f2h(hv.y), f2h(hv.z), f2h(hv.w));
  float4 a1 = ((const float4*)asv)[lane];
  float4 a2 = ((const float4*)adv)[lane];
  float d1 = hv.x * a1.x + hv.y * a1.y + hv.z * a1.z + hv.w * a1.w;
  float d2 = hv.x * a2.x + hv.y * a2.y + hv.z * a2.z + hv.w * a2.w;
  for (int o = 32; o > 0; o >>= 1) {
    d1 += __shfl_down(d1, o);
    d2 += __shfl_down(d2, o);
  }
  if (lane == 0) { ssrc[wid] = d1; sdst[wid] = d2; }
}

// ---------------------------------------------------------------------------
// Weight prep: fold normalization into W (fp16 Wt transposed + cvec).
__global__ __launch_bounds__(256) void prep_k(
    const float* __restrict__ W, const float* __restrict__ sums,
    const float* __restrict__ sqs, float invN,
    unsigned short* __restrict__ Wt, float* __restrict__ cvec) {
  int n = blockIdx.x;
  int k = threadIdx.x;
  float mu = sums[k] * invN;
  float var = sqs[k] * invN - mu * mu;
  float istd = rsqrtf(var + 1e-5f);
  float w = W[(size_t)k * 256 + n] * istd;
  Wt[(size_t)n * 256 + k] = f2h(w);
  __shared__ float red[256];
  red[k] = mu * w;
  __syncthreads();
  for (int s = 128; s > 0; s >>= 1) {
    if (k < s) red[k] += red[k + s];
    __syncthreads();
  }
  if (k == 0) cvec[n] = -red[0];
}

// ---------------------------------------------------------------------------
// MFMA fp16 GEMM + fused attention dots (row-order agnostic).
__global__ __launch_bounds__(256) void gemm_mfma(
    const unsigned short* __restrict__ A, const unsigned short* __restrict__ Wt,
    const float* __restrict__ cvec, const float* __restrict__ asv,
    const float* __restrict__ adv, unsigned short* __restrict__ H,
    float* __restrict__ ssrc, float* __restrict__ sdst, int M) {
  __shared__ unsigned short Bs[2][256 * 32];  // 16 KB per buffer
  int tid = threadIdx.x;
  int wave = tid >> 6, lane = tid & 63;
  int m0 = blockIdx.x * 64 + wave * 16;
  int row = lane & 15, quad = lane >> 4;

#pragma unroll
  for (int i = 0; i < 4; i++) {
    int c = i * 256 + tid;
    f16x8 v = *(const f16x8*)(const void*)(Wt + (size_t)(c >> 2) * 256 + (c & 3) * 8);
    *(f16x8*)(void*)(&Bs[0][c * 8]) = v;
  }
  __syncthreads();

  const unsigned short* Ap = A + (size_t)(m0 + row) * 256 + quad * 8;
  f32x4 acc[16] = {};
  for (int j = 0; j < 8; j++) {
    f16x8 pf[4];
    if (j < 7) {
#pragma unroll
      for (int i = 0; i < 4; i++) {
        int c = i * 256 + tid;
        pf[i] = *(const f16x8*)(const void*)(Wt + (size_t)(c >> 2) * 256 +
                                             (j + 1) * 32 + (c & 3) * 8);
      }
    }
    f16x8 a = *(const f16x8*)(const void*)(Ap + j * 32);
    const unsigned short* bs = Bs[j & 1];
#pragma unroll
    for (int nt = 0; nt < 16; nt++) {
      f16x8 b = *(const f16x8*)(const void*)(bs + (nt * 16 + row) * 32 + quad * 8);
      acc[nt] = __builtin_amdgcn_mfma_f32_16x16x32_f16(a, b, acc[nt], 0, 0, 0);
    }
    if (j < 7) {
#pragma unroll
      for (int i = 0; i < 4; i++) {
        int c = i * 256 + tid;
        *(f16x8*)(void*)(&Bs[(j + 1) & 1][c * 8]) = pf[i];
      }
    }
    __syncthreads();
  }

  float sav[16], sdv[16], cv[16];
#pragma unroll
  for (int nt = 0; nt < 16; nt++) {
    sav[nt] = asv[nt * 16 + row];
    sdv[nt] = adv[nt * 16 + row];
    cv[nt] = cvec[nt * 16 + row];
  }
#pragma unroll
  for (int r = 0; r < 4; r++) {
    int mm = m0 + quad * 4 + r;
    unsigned short* out = H + (size_t)mm * 256 + row;
    float d1 = 0.f, d2 = 0.f;
#pragma unroll
    for (int nt = 0; nt < 16; nt++) {
      float hv = acc[nt][r] + cv[nt];
      out[nt * 16] = f2h(hv);
      d1 = fmaf(hv, sav[nt], d1);
      d2 = fmaf(hv, sdv[nt], d2);
    }
    for (int o = 1; o < 16; o <<= 1) {
      d1 += __shfl_xor(d1, o);
      d2 += __shfl_xor(d2, o);
    }
    if (row == 0) { ssrc[mm] = d1; sdst[mm] = d2; }
  }
}

// ---------------------------------------------------------------------------
// BASE-graph bucketing (topology replicated across the 128 graphs).
__global__ void base_bucket_k(
    const int* __restrict__ esrc, const int* __restrict__ edst, int Eb,
    int* __restrict__ bdeg, int* __restrict__ bebkt, int estride,
    const int* __restrict__ cluster, int Nb,
    int* __restrict__ bccnt, int* __restrict__ bcbkt) {
  int i = blockIdx.x * 256 + threadIdx.x;
  if (i < Eb) {
    int d = edst[i];
    int slot = atomicAdd(&bdeg[d], 1);
    if (slot < estride) bebkt[d * estride + slot] = esrc[i];
  }
  if (i < Nb) {
    int c = cluster[i];
    int slot = atomicAdd(&bccnt[c], 1);
    if (slot < MAXMEM) bcbkt[c * MAXMEM + slot] = i;
  }
}

// ---------------------------------------------------------------------------
// Edge scores, thread = (base dst d, graph g): normalized alpha stored at
// pw[(d*stride + j)*128 + g].
__global__ __launch_bounds__(256) void score_k(
    const int* __restrict__ bdeg, const int* __restrict__ bebkt, int estride,
    const float* __restrict__ ssrc, const float* __restrict__ sdst,
    float* __restrict__ pw, int Nb) {
  int id = blockIdx.x * 256 + threadIdx.x;
  if (id >= Nb * 128) return;
  int d = id >> 7, g = id & 127;
  int deg = bdeg[d]; if (deg > estride) deg = estride;
  float sd = sdst[d * 128 + g];
  const int* bk = bebkt + d * estride;
  float* pwr = pw + (size_t)d * estride * 128 + g;
  float sum = 0.f;
  for (int j = 0; j < deg; j++) {
    int s = bk[j];                      // uniform per d (L1 broadcast)
    float t = ssrc[s * 128 + g] + sd;   // coalesced across g
    t = t > 0.f ? t : 0.2f * t;         // leaky_relu 0.2
    float p = __expf(t);
    pwr[j * 128] = p;
    sum += p;
  }
  float inv = 1.f / sum;                // deg >= 1 (self-loop)
  for (int j = 0; j < deg; j++) pwr[j * 128] *= inv;
}

// ---------------------------------------------------------------------------
// Fused GAT aggregation + bias + relu + cluster max-pool, graph-batched.
__global__ __launch_bounds__(256) void gat_pool(
    const unsigned short* __restrict__ h, const int* __restrict__ bdeg,
    const int* __restrict__ bebkt, const float* __restrict__ pw, int estride,
    const int* __restrict__ bccnt, const int* __restrict__ bcbkt,
    const float* __restrict__ bias, unsigned short* __restrict__ pooled,
    int Mb, int lgMb) {
  int b = blockIdx.x;                 // grid = Mb * 16
  int x = b & 7, t = b >> 3;
  int c = t & (Mb - 1);
  int set = x + 8 * (t >> lgMb);      // 0..15, pinned: b%8 == set%8
  int tid = threadIdx.x;
  int gl = tid >> 5;                  // graph within set (0..7)
  int ch = tid & 31;                  // channel chunk (8 fp16 = 16 B)
  int g = set * 8 + gl;
  int nm = bccnt[c]; if (nm > MAXMEM) nm = MAXMEM;
  float4 bf0 = *(const float4*)(bias + ch * 8);
  float4 bf1 = *(const float4*)(bias + ch * 8 + 4);
  __half2 hb[4] = {__floats2half2_rn(bf0.x, bf0.y), __floats2half2_rn(bf0.z, bf0.w),
                   __floats2half2_rn(bf1.x, bf1.y), __floats2half2_rn(bf1.z, bf1.w)};
  __half2 z = __float2half2_rn(0.f);
  __half2 best[4] = {z, z, z, z};     // relu folded via 0-init
  for (int mi = 0; mi < nm; mi++) {
    int nb = __builtin_amdgcn_readfirstlane(bcbkt[c * MAXMEM + mi]);
    int deg = __builtin_amdgcn_readfirstlane(bdeg[nb]);
    if (deg > estride) deg = estride;
    const int* bk = bebkt + nb * estride;                  // uniform, L1-hot
    const float* pwn = pw + (size_t)nb * estride * 128 + g;
    __half2 acc[4] = {z, z, z, z};
    int j = 0;
    for (; j + 4 <= deg; j += 4) {
      int4 ss = *(const int4*)(bk + j);                    // broadcast 16B
      float q0 = pwn[(size_t)j * 128];
      float q1 = pwn[(size_t)(j + 1) * 128];
      float q2 = pwn[(size_t)(j + 2) * 128];
      float q3 = pwn[(size_t)(j + 3) * 128];
      uint4 v0 = *(const uint4*)(h + ((size_t)ss.x * 128 + g) * DIM + ch * 8);
      uint4 v1 = *(const uint4*)(h + ((size_t)ss.y * 128 + g) * DIM + ch * 8);
      uint4 v2 = *(const uint4*)(h + ((size_t)ss.z * 128 + g) * DIM + ch * 8);
      uint4 v3 = *(const uint4*)(h + ((size_t)ss.w * 128 + g) * DIM + ch * 8);
      __half2 hq0 = __float2half2_rn(q0), hq1 = __float2half2_rn(q1);
      __half2 hq2 = __float2half2_rn(q2), hq3 = __float2half2_rn(q3);
      union { uint4 u; __half2 p[4]; } u0, u1, u2, u3;
      u0.u = v0; u1.u = v1; u2.u = v2; u3.u = v3;
#pragma unroll
      for (int i = 0; i < 4; i++) {
        acc[i] = __hfma2(u0.p[i], hq0, acc[i]);
        acc[i] = __hfma2(u1.p[i], hq1, acc[i]);
        acc[i] = __hfma2(u2.p[i], hq2, acc[i]);
        acc[i] = __hfma2(u3.p[i], hq3, acc[i]);
      }
    }
    for (; j < deg; j++) {
      int s = bk[j];
      float q = pwn[(size_t)j * 128];
      uint4 v0 = *(const uint4*)(h + ((size_t)s * 128 + g) * DIM + ch * 8);
      __half2 hq = __float2half2_rn(q);
      union { uint4 u; __half2 p[4]; } u0; u0.u = v0;
#pragma unroll
      for (int i = 0; i < 4; i++) acc[i] = __hfma2(u0.p[i], hq, acc[i]);
    }
#pragma unroll
    for (int i = 0; i < 4; i++)
      best[i] = hmax2_(best[i], __hadd2(acc[i], hb[i]));
  }
  union { uint4 u; __half2 p[4]; } o;
#pragma unroll
  for (int i = 0; i < 4; i++) o.p[i] = best[i];
  *(uint4*)(pooled + ((size_t)c * 128 + g) * DIM + ch * 8) = o.u;
}

// ---------------------------------------------------------------------------
// Channel sums/sq-sums over M rows. Thread = (row-group rg, channel-chunk ch):
// each block-iteration reads 8 contiguous rows = 4 KB coalesced uint4 loads;
// fp32 partials in registers; end-of-block LDS-atomic reduce + 2 global
// atomics per channel.
__global__ __launch_bounds__(256) void stats_k(
    const unsigned short* __restrict__ x, float* __restrict__ sums,
    float* __restrict__ sqs, int M) {
  int tid = threadIdx.x;
  int ch = tid & 31;   // 8 channels: ch*8 .. ch*8+7
  int rg = tid >> 5;   // row group 0..7
  float s[8] = {}, q[8] = {};
  for (int r = blockIdx.x * 8 + rg; r < M; r += gridDim.x * 8) {
    uint4 v = *(const uint4*)(x + (size_t)r * DIM + ch * 8);
    union { uint4 u; __half2 p[4]; } uu; uu.u = v;
#pragma unroll
    for (int i = 0; i < 4; i++) {
      float2 f = __half22float2(uu.p[i]);
      s[2 * i]     += f.x; q[2 * i]     = fmaf(f.x, f.x, q[2 * i]);
      s[2 * i + 1] += f.y; q[2 * i + 1] = fmaf(f.y, f.y, q[2 * i + 1]);
    }
  }
  __shared__ float sm[512];
  sm[tid] = 0.f; sm[tid + 256] = 0.f;
  __syncthreads();
#pragma unroll
  for (int i = 0; i < 8; i++) {
    atomicAdd(&sm[ch * 8 + i], s[i]);
    atomicAdd(&sm[256 + ch * 8 + i], q[i]);
  }
  __syncthreads();
  atomicAdd(&sums[tid], sm[tid]);
  atomicAdd(&sqs[tid], sm[tid + 256]);
}

// Final normalize: fp16 pooled (base-major) -> fp32 d_out (graph-major).
__global__ void norm_out(const unsigned short* __restrict__ xin,
                         float* __restrict__ xout,
                         const float* __restrict__ sums, const float* __restrict__ sqs,
                         float invN, int Mb, int total) {
  int idx = blockIdx.x * 256 + threadIdx.x;
  if (idx >= total) return;
  int ch = idx & 255;
  int r = idx >> 8;            // r = c*128 + g
  int g = r & 127, c = r >> 7;
  float mu = sums[ch] * invN;
  float var = sqs[ch] * invN - mu * mu;
  float v = (h2f(xin[idx]) - mu) * rsqrtf(var + 1e-5f);
  xout[((size_t)g * Mb + c) * 256 + ch] = v;
}

// ---------------------------------------------------------------------------
extern "C" void kernel_launch(void* const* d_in, const int* in_sizes, int n_in,
                              void* d_out, int out_size, void* d_ws, size_t ws_size,
                              hipStream_t stream) {
  const int B = 128;
  const int Nb[4] = {706, 512, 256, 128};          // base-graph sizes
  const int Ns[4] = {128 * 706, 128 * 512, 128 * 256, 128 * 128};
  const int lgMb[3] = {9, 8, 7};                   // log2(Nb[L+1])
  const int EST[3] = {64, 160, 288};               // base in-degree strides

  int iW[3], iA[3], iD[3], iB_[3], iE[3], iC[3];
  if (in_sizes[2] == 256) {  // dict order
    for (int i = 0; i < 3; i++) {
      iW[i] = 1 + 6 * i; iA[i] = 2 + 6 * i; iD[i] = 3 + 6 * i;
      iB_[i] = 4 + 6 * i; iE[i] = 5 + 6 * i; iC[i] = 6 + 6 * i;
    }
  } else {
    for (int i = 0; i < 3; i++) {
      iW[i] = 1 + i; iA[i] = 4 + i; iD[i] = 7 + i;
      iB_[i] = 10 + i; iE[i] = 13 + i; iC[i] = 16 + i;
    }
  }
  int E[3];
  for (int i = 0; i < 3; i++) E[i] = in_sizes[iE[i]] / 2;

  size_t pwWords = 0;
  for (int i = 0; i < 3; i++) {
    size_t w = (size_t)Ns[i] * EST[i];
    if (w > pwWords) pwWords = w;
  }
  size_t bebktWords = 0;
  for (int i = 0; i < 3; i++) {
    size_t w = (size_t)Nb[i] * EST[i];
    if (w > bebktWords) bebktWords = w;
  }

  char* wsp = (char*)d_ws;
  size_t o = 0;
  auto alloc = [&](size_t bytes) -> void* {
    void* p = wsp + o;
    o = (o + bytes + 255) & ~(size_t)255;
    return p;
  };
  unsigned short* h      = (unsigned short*)alloc((size_t)Ns[0] * DIM * 2);  // 46 MB
  unsigned short* pooled = (unsigned short*)alloc((size_t)Ns[1] * DIM * 2);  // 33.5 MB
  float* ssrc   = (float*)alloc((size_t)Ns[0] * 4);
  float* sdst   = (float*)alloc((size_t)Ns[0] * 4);
  float* pw     = (float*)alloc(pwWords * 4);                    // 42 MB
  int*   bmeta  = (int*)alloc((size_t)(Nb[0] + Nb[1]) * 4);      // bdeg|bccnt
  int*   bebkt  = (int*)alloc(bebktWords * 4);                   // ~300 KB
  int*   bcbkt  = (int*)alloc((size_t)Nb[1] * MAXMEM * 4);       // 32 KB
  float* statbuf= (float*)alloc(3 * 512 * 4);
  unsigned short* Wt = (unsigned short*)alloc(256 * 256 * 2);
  float* cvec   = (float*)alloc(256 * 4);
  (void)ws_size; (void)n_in; (void)out_size;

  int* bdeg = bmeta;
  int* bccnt = bmeta + Nb[0];
  const float* xin = (const float*)d_in[0];

  hipMemsetAsync(statbuf, 0, 3 * 512 * 4, stream);

  for (int L = 0; L < 3; L++) {
    int N = Ns[L], M = Ns[L + 1];
    int NbL = Nb[L], Eb = E[L] / B;
    const float* W  = (const float*)d_in[iW[L]];
    const float* av = (const float*)d_in[iA[L]];
    const float* dv = (const float*)d_in[iD[L]];
    const float* bv = (const float*)d_in[iB_[L]];
    const int* esrc = (const int*)d_in[iE[L]];
    const int* edst = esrc + E[L];
    const int* cl   = (const int*)d_in[iC[L]];
    float* sums = statbuf + L * 512;
    float* sqs  = sums + 256;

    hipMemsetAsync(bmeta, 0, (size_t)(Nb[0] + Nb[1]) * 4, stream);
    int gmax = Eb > NbL ? Eb : NbL;
    base_bucket_k<<<(gmax + 255) / 256, 256, 0, stream>>>(
        esrc, edst, Eb, bdeg, bebkt, EST[L], cl, NbL, bccnt, bcbkt);

    if (L == 0) {
      l0_fused<<<(N + 3) / 4, 256, 0, stream>>>(xin, W, av, dv, h, ssrc, sdst,
                                                N, NbL);
    } else {
      float* psums = statbuf + (L - 1) * 512;
      prep_k<<<256, 256, 0, stream>>>(W, psums, psums + 256, 1.0f / (float)N,
                                      Wt, cvec);
      gemm_mfma<<<N / 64, 256, 0, stream>>>(pooled, Wt, cvec, av, dv,
                                            h, ssrc, sdst, N);
    }

    score_k<<<(NbL * 128 + 255) / 256, 256, 0, stream>>>(
        bdeg, bebkt, EST[L], ssrc, sdst, pw, NbL);

    int MbL = Nb[L + 1];
    gat_pool<<<MbL * 16, 256, 0, stream>>>(h, bdeg, bebkt, pw, EST[L],
                                           bccnt, bcbkt, bv, pooled,
                                           MbL, lgMb[L]);

    stats_k<<<512, 256, 0, stream>>>(pooled, sums, sqs, M);
  }

  norm_out<<<((size_t)Ns[3] * DIM + 255) / 256, 256, 0, stream>>>(
      pooled, (float*)d_out, statbuf + 2 * 512, statbuf + 2 * 512 + 256,
      1.0f / (float)Ns[3], Nb[3], Ns[3] * DIM);
}

// Round 13
// 411.872 us; speedup vs baseline: 1.1492x; 1.0107x over previous
//
#include <hip/hip_runtime.h>
#include <hip/hip_fp16.h>

#define DIM 256
#define MAXMEM 16

typedef _Float16 f16x8 __attribute__((ext_vector_type(8)));
typedef float f32x4 __attribute__((ext_vector_type(4)));

__device__ inline unsigned short f2h(float f) {
  return __half_as_ushort(__float2half_rn(f));
}
__device__ inline float h2f(unsigned short u) {
  return __half2float(__ushort_as_half(u));
}
__device__ inline __half2 hmax2_(__half2 a, __half2 b) {
  __half2 c;
  c.x = __hgt(a.x, b.x) ? a.x : b.x;
  c.y = __hgt(a.y, b.y) ? a.y : b.y;
  return c;
}

// ---------------------------------------------------------------------------
// NODE ORDERING: base-major. Global row of (base node nb, graph g) = nb*128+g.
// ---------------------------------------------------------------------------

// Layer-0 fused: h = x @ W (fp16 out, base-major rows) + attention dots.
__global__ __launch_bounds__(256) void l0_fused(
    const float* __restrict__ x, const float* __restrict__ W,
    const float* __restrict__ asv, const float* __restrict__ adv,
    unsigned short* __restrict__ h, float* __restrict__ ssrc,
    float* __restrict__ sdst, int N, int Nb0) {
  int wid = (blockIdx.x * 256 + threadIdx.x) >> 6;  // nb*128+g
  int lane = threadIdx.x & 63;
  if (wid >= N) return;
  int nb = wid >> 7, g = wid & 127;
  const float* xr = x + ((size_t)g * Nb0 + nb) * 3;  // reference is graph-major
  float x0 = xr[0], x1 = xr[1], x2 = xr[2];
  int c = lane * 4;
  float4 w0 = *(const float4*)(W + c);
  float4 w1 = *(const float4*)(W + 256 + c);
  float4 w2 = *(const float4*)(W + 512 + c);
  float4 hv;
  hv.x = fmaf(x0, w0.x, fmaf(x1, w1.x, x2 * w2.x));
  hv.y = fmaf(x0, w0.y, fmaf(x1, w1.y, x2 * w2.y));
  hv.z = fmaf(x0, w0.z, fmaf(x1, w1.z, x2 * w2.z));
  hv.w = fmaf(x0, w0.w, fmaf(x1, w1.w, x2 * w2.w));
  ((ushort4*)(h + (size_t)wid * DIM))[lane] =
      make_ushort4(f2h(hv.x), f2h(hv.y), f2h(hv.z), f2h(hv.w));
  float4 a1 = ((const float4*)asv)[lane];
  float4 a2 = ((const float4*)adv)[lane];
  float d1 = hv.x * a1.x + hv.y * a1.y + hv.z * a1.z + hv.w * a1.w;
  float d2 = hv.x * a2.x + hv.y * a2.y + hv.z * a2.z + hv.w * a2.w;
  for (int o = 32; o > 0; o >>= 1) {
    d1 += __shfl_down(d1, o);
    d2 += __shfl_down(d2, o);
  }
  if (lane == 0) { ssrc[wid] = d1; sdst[wid] = d2; }
}

// ---------------------------------------------------------------------------
// Weight prep: fold normalization into W (fp16 Wt transposed + cvec).
__global__ __launch_bounds__(256) void prep_k(
    const float* __restrict__ W, const float* __restrict__ sums,
    const float* __restrict__ sqs, float invN,
    unsigned short* __restrict__ Wt, float* __restrict__ cvec) {
  int n = blockIdx.x;
  int k = threadIdx.x;
  float mu = sums[k] * invN;
  float var = sqs[k] * invN - mu * mu;
  float istd = rsqrtf(var + 1e-5f);
  float w = W[(size_t)k * 256 + n] * istd;
  Wt[(size_t)n * 256 + k] = f2h(w);
  __shared__ float red[256];
  red[k] = mu * w;
  __syncthreads();
  for (int s = 128; s > 0; s >>= 1) {
    if (k < s) red[k] += red[k + s];
    __syncthreads();
  }
  if (k == 0) cvec[n] = -red[0];
}

// ---------------------------------------------------------------------------
// MFMA fp16 GEMM + fused attention dots. 32-row waves (2 A-frags per B-frag:
// MFMA-bound, not ds_read-bound). Block = 4 waves x 32 rows = 128-row strip.
__global__ __launch_bounds__(256) void gemm_mfma(
    const unsigned short* __restrict__ A, const unsigned short* __restrict__ Wt,
    const float* __restrict__ cvec, const float* __restrict__ asv,
    const float* __restrict__ adv, unsigned short* __restrict__ H,
    float* __restrict__ ssrc, float* __restrict__ sdst, int M) {
  __shared__ unsigned short Bs[2][256 * 32];  // 16 KB per buffer
  int tid = threadIdx.x;
  int wave = tid >> 6, lane = tid & 63;
  int m0 = blockIdx.x * 128 + wave * 32;
  int row = lane & 15, quad = lane >> 4;

#pragma unroll
  for (int i = 0; i < 4; i++) {
    int c = i * 256 + tid;
    f16x8 v = *(const f16x8*)(const void*)(Wt + (size_t)(c >> 2) * 256 + (c & 3) * 8);
    *(f16x8*)(void*)(&Bs[0][c * 8]) = v;
  }
  __syncthreads();

  const unsigned short* Ap = A + (size_t)(m0 + row) * 256 + quad * 8;
  f32x4 acc[2][16] = {};
  for (int j = 0; j < 8; j++) {
    f16x8 pf[4];
    if (j < 7) {
#pragma unroll
      for (int i = 0; i < 4; i++) {
        int c = i * 256 + tid;
        pf[i] = *(const f16x8*)(const void*)(Wt + (size_t)(c >> 2) * 256 +
                                             (j + 1) * 32 + (c & 3) * 8);
      }
    }
    f16x8 a0 = *(const f16x8*)(const void*)(Ap + j * 32);
    f16x8 a1 = *(const f16x8*)(const void*)(Ap + 16 * 256 + j * 32);
    const unsigned short* bs = Bs[j & 1];
#pragma unroll
    for (int nt = 0; nt < 16; nt++) {
      f16x8 b = *(const f16x8*)(const void*)(bs + (nt * 16 + row) * 32 + quad * 8);
      acc[0][nt] = __builtin_amdgcn_mfma_f32_16x16x32_f16(a0, b, acc[0][nt], 0, 0, 0);
      acc[1][nt] = __builtin_amdgcn_mfma_f32_16x16x32_f16(a1, b, acc[1][nt], 0, 0, 0);
    }
    if (j < 7) {
#pragma unroll
      for (int i = 0; i < 4; i++) {
        int c = i * 256 + tid;
        *(f16x8*)(void*)(&Bs[(j + 1) & 1][c * 8]) = pf[i];
      }
    }
    __syncthreads();
  }

  float sav[16], sdv[16], cv[16];
#pragma unroll
  for (int nt = 0; nt < 16; nt++) {
    sav[nt] = asv[nt * 16 + row];
    sdv[nt] = adv[nt * 16 + row];
    cv[nt] = cvec[nt * 16 + row];
  }
#pragma unroll
  for (int sub = 0; sub < 2; sub++)
#pragma unroll
    for (int r = 0; r < 4; r++) {
      int mm = m0 + sub * 16 + quad * 4 + r;
      unsigned short* out = H + (size_t)mm * 256 + row;
      float d1 = 0.f, d2 = 0.f;
#pragma unroll
      for (int nt = 0; nt < 16; nt++) {
        float hv = acc[sub][nt][r] + cv[nt];
        out[nt * 16] = f2h(hv);
        d1 = fmaf(hv, sav[nt], d1);
        d2 = fmaf(hv, sdv[nt], d2);
      }
      for (int o = 1; o < 16; o <<= 1) {
        d1 += __shfl_xor(d1, o);
        d2 += __shfl_xor(d2, o);
      }
      if (row == 0) { ssrc[mm] = d1; sdst[mm] = d2; }
    }
}

// ---------------------------------------------------------------------------
// BASE-graph bucketing (topology replicated across the 128 graphs).
__global__ void base_bucket_k(
    const int* __restrict__ esrc, const int* __restrict__ edst, int Eb,
    int* __restrict__ bdeg, int* __restrict__ bebkt, int estride,
    const int* __restrict__ cluster, int Nb,
    int* __restrict__ bccnt, int* __restrict__ bcbkt) {
  int i = blockIdx.x * 256 + threadIdx.x;
  if (i < Eb) {
    int d = edst[i];
    int slot = atomicAdd(&bdeg[d], 1);
    if (slot < estride) bebkt[d * estride + slot] = esrc[i];
  }
  if (i < Nb) {
    int c = cluster[i];
    int slot = atomicAdd(&bccnt[c], 1);
    if (slot < MAXMEM) bcbkt[c * MAXMEM + slot] = i;
  }
}

// ---------------------------------------------------------------------------
// Edge scores, thread = (base dst d, graph g). Two passes over the (L2-hot)
// ssrc gathers: sum, then single write of NORMALIZED fp16 alpha.
__global__ __launch_bounds__(256) void score_k(
    const int* __restrict__ bdeg, const int* __restrict__ bebkt, int estride,
    const float* __restrict__ ssrc, const float* __restrict__ sdst,
    unsigned short* __restrict__ pwh, int Nb) {
  int id = blockIdx.x * 256 + threadIdx.x;
  if (id >= Nb * 128) return;
  int d = id >> 7, g = id & 127;
  int deg = bdeg[d]; if (deg > estride) deg = estride;
  float sd = sdst[d * 128 + g];
  const int* bk = bebkt + d * estride;
  unsigned short* pwr = pwh + (size_t)d * estride * 128 + g;
  float sum = 0.f;
  for (int j = 0; j < deg; j++) {
    int s = bk[j];                      // uniform per d (L1 broadcast)
    float t = ssrc[s * 128 + g] + sd;   // coalesced across g
    t = t > 0.f ? t : 0.2f * t;         // leaky_relu 0.2
    sum += __expf(t);
  }
  float inv = 1.f / sum;                // deg >= 1 (self-loop)
  for (int j = 0; j < deg; j++) {
    int s = bk[j];
    float t = ssrc[s * 128 + g] + sd;
    t = t > 0.f ? t : 0.2f * t;
    pwr[j * 128] = f2h(__expf(t) * inv);
  }
}

// ---------------------------------------------------------------------------
// Fused GAT aggregation + bias + relu + cluster max-pool, graph-batched.
// Block = (base cluster c, 8-graph set); thread = (graph, 8-channel chunk).
__global__ __launch_bounds__(256) void gat_pool(
    const unsigned short* __restrict__ h, const int* __restrict__ bdeg,
    const int* __restrict__ bebkt, const unsigned short* __restrict__ pwh,
    int estride, const int* __restrict__ bccnt, const int* __restrict__ bcbkt,
    const float* __restrict__ bias, unsigned short* __restrict__ pooled,
    int Mb, int lgMb) {
  int b = blockIdx.x;                 // grid = Mb * 16
  int x = b & 7, t = b >> 3;
  int c = t & (Mb - 1);
  int set = x + 8 * (t >> lgMb);      // 0..15, pinned: b%8 == set%8
  int tid = threadIdx.x;
  int gl = tid >> 5;                  // graph within set (0..7)
  int ch = tid & 31;                  // channel chunk (8 fp16 = 16 B)
  int g = set * 8 + gl;
  int nm = bccnt[c]; if (nm > MAXMEM) nm = MAXMEM;
  float4 bf0 = *(const float4*)(bias + ch * 8);
  float4 bf1 = *(const float4*)(bias + ch * 8 + 4);
  __half2 hb[4] = {__floats2half2_rn(bf0.x, bf0.y), __floats2half2_rn(bf0.z, bf0.w),
                   __floats2half2_rn(bf1.x, bf1.y), __floats2half2_rn(bf1.z, bf1.w)};
  __half2 z = __float2half2_rn(0.f);
  __half2 best[4] = {z, z, z, z};     // relu folded via 0-init
  for (int mi = 0; mi < nm; mi++) {
    int nb = __builtin_amdgcn_readfirstlane(bcbkt[c * MAXMEM + mi]);
    int deg = __builtin_amdgcn_readfirstlane(bdeg[nb]);
    if (deg > estride) deg = estride;
    const int* bk = bebkt + nb * estride;                  // uniform, L1-hot
    const unsigned short* pwn = pwh + (size_t)nb * estride * 128 + g;
    __half2 acc[4] = {z, z, z, z};
    int j = 0;
    for (; j + 4 <= deg; j += 4) {
      int4 ss = *(const int4*)(bk + j);                    // broadcast 16B
      __half2 hq0 = __half2half2(__ushort_as_half(pwn[(size_t)j * 128]));
      __half2 hq1 = __half2half2(__ushort_as_half(pwn[(size_t)(j + 1) * 128]));
      __half2 hq2 = __half2half2(__ushort_as_half(pwn[(size_t)(j + 2) * 128]));
      __half2 hq3 = __half2half2(__ushort_as_half(pwn[(size_t)(j + 3) * 128]));
      uint4 v0 = *(const uint4*)(h + ((size_t)ss.x * 128 + g) * DIM + ch * 8);
      uint4 v1 = *(const uint4*)(h + ((size_t)ss.y * 128 + g) * DIM + ch * 8);
      uint4 v2 = *(const uint4*)(h + ((size_t)ss.z * 128 + g) * DIM + ch * 8);
      uint4 v3 = *(const uint4*)(h + ((size_t)ss.w * 128 + g) * DIM + ch * 8);
      union { uint4 u; __half2 p[4]; } u0, u1, u2, u3;
      u0.u = v0; u1.u = v1; u2.u = v2; u3.u = v3;
#pragma unroll
      for (int i = 0; i < 4; i++) {
        acc[i] = __hfma2(u0.p[i], hq0, acc[i]);
        acc[i] = __hfma2(u1.p[i], hq1, acc[i]);
        acc[i] = __hfma2(u2.p[i], hq2, acc[i]);
        acc[i] = __hfma2(u3.p[i], hq3, acc[i]);
      }
    }
    for (; j < deg; j++) {
      int s = bk[j];
      __half2 hq = __half2half2(__ushort_as_half(pwn[(size_t)j * 128]));
      uint4 v0 = *(const uint4*)(h + ((size_t)s * 128 + g) * DIM + ch * 8);
      union { uint4 u; __half2 p[4]; } u0; u0.u = v0;
#pragma unroll
      for (int i = 0; i < 4; i++) acc[i] = __hfma2(u0.p[i], hq, acc[i]);
    }
#pragma unroll
    for (int i = 0; i < 4; i++)
      best[i] = hmax2_(best[i], __hadd2(acc[i], hb[i]));
  }
  union { uint4 u; __half2 p[4]; } o;
#pragma unroll
  for (int i = 0; i < 4; i++) o.p[i] = best[i];
  *(uint4*)(pooled + ((size_t)c * 128 + g) * DIM + ch * 8) = o.u;
}

// ---------------------------------------------------------------------------
// Channel sums/sq-sums over M rows. Thread = (row-group rg, channel-chunk ch).
__global__ __launch_bounds__(256) void stats_k(
    const unsigned short* __restrict__ x, float* __restrict__ sums,
    float* __restrict__ sqs, int M) {
  int tid = threadIdx.x;
  int ch = tid & 31;   // 8 channels: ch*8 .. ch*8+7
  int rg = tid >> 5;   // row group 0..7
  float s[8] = {}, q[8] = {};
  for (int r = blockIdx.x * 8 + rg; r < M; r += gridDim.x * 8) {
    uint4 v = *(const uint4*)(x + (size_t)r * DIM + ch * 8);
    union { uint4 u; __half2 p[4]; } uu; uu.u = v;
#pragma unroll
    for (int i = 0; i < 4; i++) {
      float2 f = __half22float2(uu.p[i]);
      s[2 * i]     += f.x; q[2 * i]     = fmaf(f.x, f.x, q[2 * i]);
      s[2 * i + 1] += f.y; q[2 * i + 1] = fmaf(f.y, f.y, q[2 * i + 1]);
    }
  }
  __shared__ float sm[512];
  sm[tid] = 0.f; sm[tid + 256] = 0.f;
  __syncthreads();
#pragma unroll
  for (int i = 0; i < 8; i++) {
    atomicAdd(&sm[ch * 8 + i], s[i]);
    atomicAdd(&sm[256 + ch * 8 + i], q[i]);
  }
  __syncthreads();
  atomicAdd(&sums[tid], sm[tid]);
  atomicAdd(&sqs[tid], sm[tid + 256]);
}

// Final normalize: fp16 pooled (base-major) -> fp32 d_out (graph-major).
__global__ void norm_out(const unsigned short* __restrict__ xin,
                         float* __restrict__ xout,
                         const float* __restrict__ sums, const float* __restrict__ sqs,
                         float invN, int Mb, int total) {
  int idx = blockIdx.x * 256 + threadIdx.x;
  if (idx >= total) return;
  int ch = idx & 255;
  int r = idx >> 8;            // r = c*128 + g
  int g = r & 127, c = r >> 7;
  float mu = sums[ch] * invN;
  float var = sqs[ch] * invN - mu * mu;
  float v = (h2f(xin[idx]) - mu) * rsqrtf(var + 1e-5f);
  xout[((size_t)g * Mb + c) * 256 + ch] = v;
}

// ---------------------------------------------------------------------------
extern "C" void kernel_launch(void* const* d_in, const int* in_sizes, int n_in,
                              void* d_out, int out_size, void* d_ws, size_t ws_size,
                              hipStream_t stream) {
  const int B = 128;
  const int Nb[4] = {706, 512, 256, 128};          // base-graph sizes
  const int Ns[4] = {128 * 706, 128 * 512, 128 * 256, 128 * 128};
  const int lgMb[3] = {9, 8, 7};                   // log2(Nb[L+1])
  const int EST[3] = {64, 160, 288};               // base in-degree strides

  int iW[3], iA[3], iD[3], iB_[3], iE[3], iC[3];
  if (in_sizes[2] == 256) {  // dict order
    for (int i = 0; i < 3; i++) {
      iW[i] = 1 + 6 * i; iA[i] = 2 + 6 * i; iD[i] = 3 + 6 * i;
      iB_[i] = 4 + 6 * i; iE[i] = 5 + 6 * i; iC[i] = 6 + 6 * i;
    }
  } else {
    for (int i = 0; i < 3; i++) {
      iW[i] = 1 + i; iA[i] = 4 + i; iD[i] = 7 + i;
      iB_[i] = 10 + i; iE[i] = 13 + i; iC[i] = 16 + i;
    }
  }
  int E[3];
  for (int i = 0; i < 3; i++) E[i] = in_sizes[iE[i]] / 2;

  size_t pwWords = 0;  // fp16 alpha elements
  for (int i = 0; i < 3; i++) {
    size_t w = (size_t)Ns[i] * EST[i];
    if (w > pwWords) pwWords = w;
  }
  int bebktOff[3], bcbktOff[3];
  size_t bebktTot = 0, bcbktTot = 0;
  for (int i = 0; i < 3; i++) {
    bebktOff[i] = (int)bebktTot; bebktTot += (size_t)Nb[i] * EST[i];
    bcbktOff[i] = (int)bcbktTot; bcbktTot += (size_t)Nb[i + 1] * MAXMEM;
  }

  char* wsp = (char*)d_ws;
  size_t o = 0;
  auto alloc = [&](size_t bytes) -> void* {
    void* p = wsp + o;
    o = (o + bytes + 255) & ~(size_t)255;
    return p;
  };
  unsigned short* h      = (unsigned short*)alloc((size_t)Ns[0] * DIM * 2);  // 46 MB
  unsigned short* pooled = (unsigned short*)alloc((size_t)Ns[1] * DIM * 2);  // 33.5 MB
  float* ssrc   = (float*)alloc((size_t)Ns[0] * 4);
  float* sdst   = (float*)alloc((size_t)Ns[0] * 4);
  unsigned short* pwh = (unsigned short*)alloc(pwWords * 2);     // 21 MB
  int*   bmeta  = (int*)alloc((size_t)3 * (Nb[0] + Nb[1]) * 4);  // deg+ccnt x3
  int*   bebkt  = (int*)alloc(bebktTot * 4);                     // ~800 KB
  int*   bcbkt  = (int*)alloc(bcbktTot * 4);                     // ~57 KB
  float* statbuf= (float*)alloc(3 * 512 * 4);
  unsigned short* Wt = (unsigned short*)alloc(256 * 256 * 2);
  float* cvec   = (float*)alloc(256 * 4);
  (void)ws_size; (void)n_in; (void)out_size;

  // Per-layer meta: bdeg_L at bmeta + L*(Nb0+Nb1), bccnt_L right after.
  const float* xin = (const float*)d_in[0];

  hipMemsetAsync(statbuf, 0, 3 * 512 * 4, stream);
  hipMemsetAsync(bmeta, 0, (size_t)3 * (Nb[0] + Nb[1]) * 4, stream);

  // Hoisted: all three base-graph bucket builds (no data dependencies).
  for (int L = 0; L < 3; L++) {
    int NbL = Nb[L], Eb = E[L] / B;
    const int* esrc = (const int*)d_in[iE[L]];
    const int* edst = esrc + E[L];
    const int* cl   = (const int*)d_in[iC[L]];
    int* bdeg = bmeta + L * (Nb[0] + Nb[1]);
    int* bccnt = bdeg + NbL;
    int gmax = Eb > NbL ? Eb : NbL;
    base_bucket_k<<<(gmax + 255) / 256, 256, 0, stream>>>(
        esrc, edst, Eb, bdeg, bebkt + bebktOff[L], EST[L], cl, NbL,
        bccnt, bcbkt + bcbktOff[L]);
  }

  for (int L = 0; L < 3; L++) {
    int N = Ns[L], M = Ns[L + 1];
    int NbL = Nb[L];
    const float* W  = (const float*)d_in[iW[L]];
    const float* av = (const float*)d_in[iA[L]];
    const float* dv = (const float*)d_in[iD[L]];
    const float* bv = (const float*)d_in[iB_[L]];
    float* sums = statbuf + L * 512;
    float* sqs  = sums + 256;
    int* bdeg = bmeta + L * (Nb[0] + Nb[1]);
    int* bccnt = bdeg + NbL;
    int* beb = bebkt + bebktOff[L];
    int* bcb = bcbkt + bcbktOff[L];

    if (L == 0) {
      l0_fused<<<(N + 3) / 4, 256, 0, stream>>>(xin, W, av, dv, h, ssrc, sdst,
                                                N, NbL);
    } else {
      float* psums = statbuf + (L - 1) * 512;
      prep_k<<<256, 256, 0, stream>>>(W, psums, psums + 256, 1.0f / (float)N,
                                      Wt, cvec);
      gemm_mfma<<<N / 128, 256, 0, stream>>>(pooled, Wt, cvec, av, dv,
                                             h, ssrc, sdst, N);
    }

    score_k<<<(NbL * 128 + 255) / 256, 256, 0, stream>>>(
        bdeg, beb, EST[L], ssrc, sdst, pwh, NbL);

    int MbL = Nb[L + 1];
    gat_pool<<<MbL * 16, 256, 0, stream>>>(h, bdeg, beb, pwh, EST[L],
                                           bccnt, bcb, bv, pooled,
                                           MbL, lgMb[L]);

    stats_k<<<512, 256, 0, stream>>>(pooled, sums, sqs, M);
  }

  norm_out<<<((size_t)Ns[3] * DIM + 255) / 256, 256, 0, stream>>>(
      pooled, (float*)d_out, statbuf + 2 * 512, statbuf + 2 * 512 + 256,
      1.0f / (float)Ns[3], Nb[3], Ns[3] * DIM);
}

// Round 14
// 344.705 us; speedup vs baseline: 1.3731x; 1.1949x over previous
//
#include <hip/hip_runtime.h>
#include <hip/hip_fp16.h>

#define DIM 256
#define MAXMEM 16
#define MAXDEG 288

typedef _Float16 f16x8 __attribute__((ext_vector_type(8)));
typedef float f32x4 __attribute__((ext_vector_type(4)));

__device__ inline unsigned short f2h(float f) {
  return __half_as_ushort(__float2half_rn(f));
}
__device__ inline float h2f(unsigned short u) {
  return __half2float(__ushort_as_half(u));
}
__device__ inline __half2 hmax2_(__half2 a, __half2 b) {
  __half2 c;
  c.x = __hgt(a.x, b.x) ? a.x : b.x;
  c.y = __hgt(a.y, b.y) ? a.y : b.y;
  return c;
}

// ---------------------------------------------------------------------------
// NODE ORDERING: base-major. Global row of (base node nb, graph g) = nb*128+g.
// ---------------------------------------------------------------------------

// Layer-0 fused: h = x @ W (fp16 out, base-major rows) + attention dots.
__global__ __launch_bounds__(256) void l0_fused(
    const float* __restrict__ x, const float* __restrict__ W,
    const float* __restrict__ asv, const float* __restrict__ adv,
    unsigned short* __restrict__ h, float* __restrict__ ssrc,
    float* __restrict__ sdst, int N, int Nb0) {
  int wid = (blockIdx.x * 256 + threadIdx.x) >> 6;  // nb*128+g
  int lane = threadIdx.x & 63;
  if (wid >= N) return;
  int nb = wid >> 7, g = wid & 127;
  const float* xr = x + ((size_t)g * Nb0 + nb) * 3;  // reference is graph-major
  float x0 = xr[0], x1 = xr[1], x2 = xr[2];
  int c = lane * 4;
  float4 w0 = *(const float4*)(W + c);
  float4 w1 = *(const float4*)(W + 256 + c);
  float4 w2 = *(const float4*)(W + 512 + c);
  float4 hv;
  hv.x = fmaf(x0, w0.x, fmaf(x1, w1.x, x2 * w2.x));
  hv.y = fmaf(x0, w0.y, fmaf(x1, w1.y, x2 * w2.y));
  hv.z = fmaf(x0, w0.z, fmaf(x1, w1.z, x2 * w2.z));
  hv.w = fmaf(x0, w0.w, fmaf(x1, w1.w, x2 * w2.w));
  ((ushort4*)(h + (size_t)wid * DIM))[lane] =
      make_ushort4(f2h(hv.x), f2h(hv.y), f2h(hv.z), f2h(hv.w));
  float4 a1 = ((const float4*)asv)[lane];
  float4 a2 = ((const float4*)adv)[lane];
  float d1 = hv.x * a1.x + hv.y * a1.y + hv.z * a1.z + hv.w * a1.w;
  float d2 = hv.x * a2.x + hv.y * a2.y + hv.z * a2.z + hv.w * a2.w;
  for (int o = 32; o > 0; o >>= 1) {
    d1 += __shfl_down(d1, o);
    d2 += __shfl_down(d2, o);
  }
  if (lane == 0) { ssrc[wid] = d1; sdst[wid] = d2; }
}

// ---------------------------------------------------------------------------
// Weight prep: fold normalization into W (fp16 Wt transposed + cvec).
__global__ __launch_bounds__(256) void prep_k(
    const float* __restrict__ W, const float* __restrict__ sums,
    const float* __restrict__ sqs, float invN,
    unsigned short* __restrict__ Wt, float* __restrict__ cvec) {
  int n = blockIdx.x;
  int k = threadIdx.x;
  float mu = sums[k] * invN;
  float var = sqs[k] * invN - mu * mu;
  float istd = rsqrtf(var + 1e-5f);
  float w = W[(size_t)k * 256 + n] * istd;
  Wt[(size_t)n * 256 + k] = f2h(w);
  __shared__ float red[256];
  red[k] = mu * w;
  __syncthreads();
  for (int s = 128; s > 0; s >>= 1) {
    if (k < s) red[k] += red[k + s];
    __syncthreads();
  }
  if (k == 0) cvec[n] = -red[0];
}

// ---------------------------------------------------------------------------
// MFMA fp16 GEMM + fused attention dots. 32-row waves (2 A-frags per B-frag).
__global__ __launch_bounds__(256) void gemm_mfma(
    const unsigned short* __restrict__ A, const unsigned short* __restrict__ Wt,
    const float* __restrict__ cvec, const float* __restrict__ asv,
    const float* __restrict__ adv, unsigned short* __restrict__ H,
    float* __restrict__ ssrc, float* __restrict__ sdst, int M) {
  __shared__ unsigned short Bs[2][256 * 32];  // 16 KB per buffer
  int tid = threadIdx.x;
  int wave = tid >> 6, lane = tid & 63;
  int m0 = blockIdx.x * 128 + wave * 32;
  int row = lane & 15, quad = lane >> 4;

#pragma unroll
  for (int i = 0; i < 4; i++) {
    int c = i * 256 + tid;
    f16x8 v = *(const f16x8*)(const void*)(Wt + (size_t)(c >> 2) * 256 + (c & 3) * 8);
    *(f16x8*)(void*)(&Bs[0][c * 8]) = v;
  }
  __syncthreads();

  const unsigned short* Ap = A + (size_t)(m0 + row) * 256 + quad * 8;
  f32x4 acc[2][16] = {};
  for (int j = 0; j < 8; j++) {
    f16x8 pf[4];
    if (j < 7) {
#pragma unroll
      for (int i = 0; i < 4; i++) {
        int c = i * 256 + tid;
        pf[i] = *(const f16x8*)(const void*)(Wt + (size_t)(c >> 2) * 256 +
                                             (j + 1) * 32 + (c & 3) * 8);
      }
    }
    f16x8 a0 = *(const f16x8*)(const void*)(Ap + j * 32);
    f16x8 a1 = *(const f16x8*)(const void*)(Ap + 16 * 256 + j * 32);
    const unsigned short* bs = Bs[j & 1];
#pragma unroll
    for (int nt = 0; nt < 16; nt++) {
      f16x8 b = *(const f16x8*)(const void*)(bs + (nt * 16 + row) * 32 + quad * 8);
      acc[0][nt] = __builtin_amdgcn_mfma_f32_16x16x32_f16(a0, b, acc[0][nt], 0, 0, 0);
      acc[1][nt] = __builtin_amdgcn_mfma_f32_16x16x32_f16(a1, b, acc[1][nt], 0, 0, 0);
    }
    if (j < 7) {
#pragma unroll
      for (int i = 0; i < 4; i++) {
        int c = i * 256 + tid;
        *(f16x8*)(void*)(&Bs[(j + 1) & 1][c * 8]) = pf[i];
      }
    }
    __syncthreads();
  }

  float sav[16], sdv[16], cv[16];
#pragma unroll
  for (int nt = 0; nt < 16; nt++) {
    sav[nt] = asv[nt * 16 + row];
    sdv[nt] = adv[nt * 16 + row];
    cv[nt] = cvec[nt * 16 + row];
  }
#pragma unroll
  for (int sub = 0; sub < 2; sub++)
#pragma unroll
    for (int r = 0; r < 4; r++) {
      int mm = m0 + sub * 16 + quad * 4 + r;
      unsigned short* out = H + (size_t)mm * 256 + row;
      float d1 = 0.f, d2 = 0.f;
#pragma unroll
      for (int nt = 0; nt < 16; nt++) {
        float hv = acc[sub][nt][r] + cv[nt];
        out[nt * 16] = f2h(hv);
        d1 = fmaf(hv, sav[nt], d1);
        d2 = fmaf(hv, sdv[nt], d2);
      }
      for (int o = 1; o < 16; o <<= 1) {
        d1 += __shfl_xor(d1, o);
        d2 += __shfl_xor(d2, o);
      }
      if (row == 0) { ssrc[mm] = d1; sdst[mm] = d2; }
    }
}

// ---------------------------------------------------------------------------
// All 3 layers' base-graph bucketing in ONE launch (blockIdx.y = layer).
struct BktArgs {
  const int* esrc[3]; const int* edst[3]; const int* cl[3];
  int Eb[3]; int Nb[3]; int est[3];
  int* bdeg[3]; int* bccnt[3]; int* bebkt[3]; int* bcbkt[3];
};
__global__ void bucket3_k(BktArgs a) {
  int L = blockIdx.y;
  int i = blockIdx.x * 256 + threadIdx.x;
  if (i < a.Eb[L]) {
    int d = a.edst[L][i];
    int slot = atomicAdd(&a.bdeg[L][d], 1);
    if (slot < a.est[L]) a.bebkt[L][d * a.est[L] + slot] = a.esrc[L][i];
  }
  if (i < a.Nb[L]) {
    int c = a.cl[L][i];
    int slot = atomicAdd(&a.bccnt[L][c], 1);
    if (slot < MAXMEM) a.bcbkt[L][c * MAXMEM + slot] = i;
  }
}

// ---------------------------------------------------------------------------
// FUSED: edge softmax (fp32, in LDS) + GAT aggregation + bias + relu +
// cluster max-pool, graph-batched. Block = (base cluster c, 8-graph set);
// thread = (graph gl, 8-channel chunk ch). Each (dst,graph) is scored exactly
// once — in the block owning its cluster. No pw global round-trip.
__global__ __launch_bounds__(256) void gat_fused(
    const unsigned short* __restrict__ h, const int* __restrict__ bdeg,
    const int* __restrict__ bebkt, int estride,
    const int* __restrict__ bccnt, const int* __restrict__ bcbkt,
    const float* __restrict__ ssrc, const float* __restrict__ sdst,
    const float* __restrict__ bias, unsigned short* __restrict__ pooled,
    int Mb, int lgMb) {
  __shared__ float pLDS[MAXDEG * 8];  // p[j][g_local], fp32
  __shared__ float psum[8];
  int b = blockIdx.x;                 // grid = Mb * 16
  int x = b & 7, t = b >> 3;
  int c = t & (Mb - 1);
  int set = x + 8 * (t >> lgMb);      // 0..15, pinned: b%8 == set%8
  int tid = threadIdx.x;
  int gl = tid >> 5;                  // graph within set (0..7)
  int ch = tid & 31;                  // channel chunk (8 fp16 = 16 B)
  int g = set * 8 + gl;
  int nm = bccnt[c]; if (nm > MAXMEM) nm = MAXMEM;
  float4 bf0 = *(const float4*)(bias + ch * 8);
  float4 bf1 = *(const float4*)(bias + ch * 8 + 4);
  __half2 hb[4] = {__floats2half2_rn(bf0.x, bf0.y), __floats2half2_rn(bf0.z, bf0.w),
                   __floats2half2_rn(bf1.x, bf1.y), __floats2half2_rn(bf1.z, bf1.w)};
  __half2 z = __float2half2_rn(0.f);
  __half2 best[4] = {z, z, z, z};     // relu folded via 0-init
  for (int mi = 0; mi < nm; mi++) {
    int nb = __builtin_amdgcn_readfirstlane(bcbkt[c * MAXMEM + mi]);
    int deg = __builtin_amdgcn_readfirstlane(bdeg[nb]);
    if (deg > estride) deg = estride;
    const int* bk = bebkt + nb * estride;                  // uniform, L1-hot
    // Phase 1: scores for this member, all 8 graphs, lane-parallel.
    if (tid < 8) psum[tid] = 0.f;
    __syncthreads();
    for (int jj = tid; jj < deg * 8; jj += 256) {
      int j = jj >> 3, gi = jj & 7;
      int g2 = set * 8 + gi;
      int s = bk[j];
      float tt = ssrc[s * 128 + g2] + sdst[nb * 128 + g2];
      tt = tt > 0.f ? tt : 0.2f * tt;  // leaky_relu 0.2
      float p = __expf(tt);
      pLDS[jj] = p;
      atomicAdd(&psum[gi], p);
    }
    __syncthreads();
    float inv = 1.f / psum[gl];        // deg >= 1 (self-loop)
    // Phase 2: aggregation (alpha = pLDS * inv, fp32 -> fp16 per edge).
    __half2 acc[4] = {z, z, z, z};
    int j = 0;
    for (; j + 4 <= deg; j += 4) {
      int4 ss = *(const int4*)(bk + j);                    // broadcast 16B
      __half2 hq0 = __float2half2_rn(pLDS[(j + 0) * 8 + gl] * inv);
      __half2 hq1 = __float2half2_rn(pLDS[(j + 1) * 8 + gl] * inv);
      __half2 hq2 = __float2half2_rn(pLDS[(j + 2) * 8 + gl] * inv);
      __half2 hq3 = __float2half2_rn(pLDS[(j + 3) * 8 + gl] * inv);
      uint4 v0 = *(const uint4*)(h + ((size_t)ss.x * 128 + g) * DIM + ch * 8);
      uint4 v1 = *(const uint4*)(h + ((size_t)ss.y * 128 + g) * DIM + ch * 8);
      uint4 v2 = *(const uint4*)(h + ((size_t)ss.z * 128 + g) * DIM + ch * 8);
      uint4 v3 = *(const uint4*)(h + ((size_t)ss.w * 128 + g) * DIM + ch * 8);
      union { uint4 u; __half2 p[4]; } u0, u1, u2, u3;
      u0.u = v0; u1.u = v1; u2.u = v2; u3.u = v3;
#pragma unroll
      for (int i = 0; i < 4; i++) {
        acc[i] = __hfma2(u0.p[i], hq0, acc[i]);
        acc[i] = __hfma2(u1.p[i], hq1, acc[i]);
        acc[i] = __hfma2(u2.p[i], hq2, acc[i]);
        acc[i] = __hfma2(u3.p[i], hq3, acc[i]);
      }
    }
    for (; j < deg; j++) {
      int s = bk[j];
      __half2 hq = __float2half2_rn(pLDS[j * 8 + gl] * inv);
      uint4 v0 = *(const uint4*)(h + ((size_t)s * 128 + g) * DIM + ch * 8);
      union { uint4 u; __half2 p[4]; } u0; u0.u = v0;
#pragma unroll
      for (int i = 0; i < 4; i++) acc[i] = __hfma2(u0.p[i], hq, acc[i]);
    }
#pragma unroll
    for (int i = 0; i < 4; i++)
      best[i] = hmax2_(best[i], __hadd2(acc[i], hb[i]));
    __syncthreads();  // protect pLDS/psum before next member overwrites
  }
  union { uint4 u; __half2 p[4]; } o;
#pragma unroll
  for (int i = 0; i < 4; i++) o.p[i] = best[i];
  *(uint4*)(pooled + ((size_t)c * 128 + g) * DIM + ch * 8) = o.u;
}

// ---------------------------------------------------------------------------
// Channel sums/sq-sums over M rows. Thread = (row-group rg, channel-chunk ch).
__global__ __launch_bounds__(256) void stats_k(
    const unsigned short* __restrict__ x, float* __restrict__ sums,
    float* __restrict__ sqs, int M) {
  int tid = threadIdx.x;
  int ch = tid & 31;   // 8 channels: ch*8 .. ch*8+7
  int rg = tid >> 5;   // row group 0..7
  float s[8] = {}, q[8] = {};
  for (int r = blockIdx.x * 8 + rg; r < M; r += gridDim.x * 8) {
    uint4 v = *(const uint4*)(x + (size_t)r * DIM + ch * 8);
    union { uint4 u; __half2 p[4]; } uu; uu.u = v;
#pragma unroll
    for (int i = 0; i < 4; i++) {
      float2 f = __half22float2(uu.p[i]);
      s[2 * i]     += f.x; q[2 * i]     = fmaf(f.x, f.x, q[2 * i]);
      s[2 * i + 1] += f.y; q[2 * i + 1] = fmaf(f.y, f.y, q[2 * i + 1]);
    }
  }
  __shared__ float sm[512];
  sm[tid] = 0.f; sm[tid + 256] = 0.f;
  __syncthreads();
#pragma unroll
  for (int i = 0; i < 8; i++) {
    atomicAdd(&sm[ch * 8 + i], s[i]);
    atomicAdd(&sm[256 + ch * 8 + i], q[i]);
  }
  __syncthreads();
  atomicAdd(&sums[tid], sm[tid]);
  atomicAdd(&sqs[tid], sm[tid + 256]);
}

// Final normalize: fp16 pooled (base-major) -> fp32 d_out (graph-major).
__global__ void norm_out(const unsigned short* __restrict__ xin,
                         float* __restrict__ xout,
                         const float* __restrict__ sums, const float* __restrict__ sqs,
                         float invN, int Mb, int total) {
  int idx = blockIdx.x * 256 + threadIdx.x;
  if (idx >= total) return;
  int ch = idx & 255;
  int r = idx >> 8;            // r = c*128 + g
  int g = r & 127, c = r >> 7;
  float mu = sums[ch] * invN;
  float var = sqs[ch] * invN - mu * mu;
  float v = (h2f(xin[idx]) - mu) * rsqrtf(var + 1e-5f);
  xout[((size_t)g * Mb + c) * 256 + ch] = v;
}

// ---------------------------------------------------------------------------
extern "C" void kernel_launch(void* const* d_in, const int* in_sizes, int n_in,
                              void* d_out, int out_size, void* d_ws, size_t ws_size,
                              hipStream_t stream) {
  const int B = 128;
  const int Nb[4] = {706, 512, 256, 128};          // base-graph sizes
  const int Ns[4] = {128 * 706, 128 * 512, 128 * 256, 128 * 128};
  const int lgMb[3] = {9, 8, 7};                   // log2(Nb[L+1])
  const int EST[3] = {64, 160, 288};               // base in-degree strides

  int iW[3], iA[3], iD[3], iB_[3], iE[3], iC[3];
  if (in_sizes[2] == 256) {  // dict order
    for (int i = 0; i < 3; i++) {
      iW[i] = 1 + 6 * i; iA[i] = 2 + 6 * i; iD[i] = 3 + 6 * i;
      iB_[i] = 4 + 6 * i; iE[i] = 5 + 6 * i; iC[i] = 6 + 6 * i;
    }
  } else {
    for (int i = 0; i < 3; i++) {
      iW[i] = 1 + i; iA[i] = 4 + i; iD[i] = 7 + i;
      iB_[i] = 10 + i; iE[i] = 13 + i; iC[i] = 16 + i;
    }
  }
  int E[3];
  for (int i = 0; i < 3; i++) E[i] = in_sizes[iE[i]] / 2;

  int bebktOff[3], bcbktOff[3];
  size_t bebktTot = 0, bcbktTot = 0;
  for (int i = 0; i < 3; i++) {
    bebktOff[i] = (int)bebktTot; bebktTot += (size_t)Nb[i] * EST[i];
    bcbktOff[i] = (int)bcbktTot; bcbktTot += (size_t)Nb[i + 1] * MAXMEM;
  }

  char* wsp = (char*)d_ws;
  size_t o = 0;
  auto alloc = [&](size_t bytes) -> void* {
    void* p = wsp + o;
    o = (o + bytes + 255) & ~(size_t)255;
    return p;
  };
  unsigned short* h      = (unsigned short*)alloc((size_t)Ns[0] * DIM * 2);  // 46 MB
  unsigned short* pooled = (unsigned short*)alloc((size_t)Ns[1] * DIM * 2);  // 33.5 MB
  float* ssrc   = (float*)alloc((size_t)Ns[0] * 4);
  float* sdst   = (float*)alloc((size_t)Ns[0] * 4);
  // statbuf + bmeta adjacent -> single memset clears both.
  float* statbuf= (float*)alloc(3 * 512 * 4);
  int*   bmeta  = (int*)alloc((size_t)3 * (Nb[0] + Nb[1]) * 4);  // deg+ccnt x3
  char*  zend   = wsp + o;   // end of zeroed region
  int*   bebkt  = (int*)alloc(bebktTot * 4);                     // ~800 KB
  int*   bcbkt  = (int*)alloc(bcbktTot * 4);                     // ~57 KB
  unsigned short* Wt = (unsigned short*)alloc(256 * 256 * 2);
  float* cvec   = (float*)alloc(256 * 4);
  (void)ws_size; (void)n_in; (void)out_size;

  const float* xin = (const float*)d_in[0];

  hipMemsetAsync(statbuf, 0, (size_t)(zend - (char*)statbuf), stream);

  // Single launch: all three base-graph bucket builds.
  BktArgs ba;
  int maxG = 0;
  for (int L = 0; L < 3; L++) {
    int Eb = E[L] / B;
    ba.esrc[L] = (const int*)d_in[iE[L]];
    ba.edst[L] = ba.esrc[L] + E[L];
    ba.cl[L]   = (const int*)d_in[iC[L]];
    ba.Eb[L] = Eb; ba.Nb[L] = Nb[L]; ba.est[L] = EST[L];
    ba.bdeg[L]  = bmeta + L * (Nb[0] + Nb[1]);
    ba.bccnt[L] = ba.bdeg[L] + Nb[L];
    ba.bebkt[L] = bebkt + bebktOff[L];
    ba.bcbkt[L] = bcbkt + bcbktOff[L];
    int gneed = (Eb > Nb[L] ? Eb : Nb[L]);
    if (gneed > maxG) maxG = gneed;
  }
  dim3 bg((maxG + 255) / 256, 3);
  bucket3_k<<<bg, 256, 0, stream>>>(ba);

  for (int L = 0; L < 3; L++) {
    int N = Ns[L], M = Ns[L + 1];
    int NbL = Nb[L];
    const float* W  = (const float*)d_in[iW[L]];
    const float* av = (const float*)d_in[iA[L]];
    const float* dv = (const float*)d_in[iD[L]];
    const float* bv = (const float*)d_in[iB_[L]];
    float* sums = statbuf + L * 512;
    float* sqs  = sums + 256;
    int* bdeg = bmeta + L * (Nb[0] + Nb[1]);
    int* bccnt = bdeg + NbL;
    int* beb = bebkt + bebktOff[L];
    int* bcb = bcbkt + bcbktOff[L];

    if (L == 0) {
      l0_fused<<<(N + 3) / 4, 256, 0, stream>>>(xin, W, av, dv, h, ssrc, sdst,
                                                N, NbL);
    } else {
      float* psums = statbuf + (L - 1) * 512;
      prep_k<<<256, 256, 0, stream>>>(W, psums, psums + 256, 1.0f / (float)N,
                                      Wt, cvec);
      gemm_mfma<<<N / 128, 256, 0, stream>>>(pooled, Wt, cvec, av, dv,
                                             h, ssrc, sdst, N);
    }

    int MbL = Nb[L + 1];
    gat_fused<<<MbL * 16, 256, 0, stream>>>(h, bdeg, beb, EST[L], bccnt, bcb,
                                            ssrc, sdst, bv, pooled,
                                            MbL, lgMb[L]);

    stats_k<<<512, 256, 0, stream>>>(pooled, sums, sqs, M);
  }

  norm_out<<<((size_t)Ns[3] * DIM + 255) / 256, 256, 0, stream>>>(
      pooled, (float*)d_out, statbuf + 2 * 512, statbuf + 2 * 512 + 256,
      1.0f / (float)Ns[3], Nb[3], Ns[3] * DIM);
}